// Round 12
// baseline (483.512 us; speedup 1.0000x reference)
//
#include <hip/hip_runtime.h>

#define BB 16
#define NN 8
#define DD 24
#define HH 48
#define WW 48
#define AA (DD*HH*WW)   // 55296
#define NSEG (AA/256)   // 216 segments per image
#define NBLK ((BB*AA)/256)  // 3456
#define TOPKc 7
#define KIGN 189        // (IGNORE_RATIO+1)*TOPK
#define NIGN 182        // exactly KIGN-TOPKc ignore marks per kept GT
#define NB1 2048        // level-1 bins = key >> 21

// fixed candidate window (shifted to stay in-grid): 13 x 25 x 25 = 8125
#define WZC 13
#define WYC 25
#define WXC 25
#define WYXC (WYC*WXC)          // 625
#define CNTC (WZC*WYXC)         // 8125
#define CPT 32                  // 32*256 = 8192 >= 8125

struct GT {
  float ctr[3];
  float half_[3];
  float bbox[6];
  float lo[3], hi[3];
  int keep, rejected;
};

struct Accum {
  int   npos[BB];
  float pos_sum[BB];
  float shape_sum, off_sum, iou_sum;
  float per_img[BB];
  int   done_img[BB*32];  // padded: one cacheline per image counter (use b*32)
  int   done;             // image-tail-done counter
};

__device__ __forceinline__ unsigned fkey(float f) {
  unsigned u = __float_as_uint(f);
  return (u & 0x80000000u) ? ~u : (u | 0x80000000u);
}
__device__ __forceinline__ float fkey_inv(unsigned k) {
  return __uint_as_float((k & 0x80000000u) ? (k & 0x7FFFFFFFu) : ~k);
}

// Wave-aggregated LDS histogram add (for heavily SKEWED bins, e.g. k3 level-1).
__device__ __forceinline__ void agg_lds_add(int* h, int bin) {
  const int lane = threadIdx.x & 63;
  unsigned long long todo = __ballot(bin >= 0);
  while (todo) {
    const int leader = __ffsll((unsigned long long)todo) - 1;
    const int lbin = __shfl(bin, leader, 64);
    const unsigned long long eq = __ballot(bin == lbin) & todo;
    if (lane == leader) atomicAdd(&h[lbin], (int)__popcll(eq));
    todo &= ~eq;
  }
}

__device__ __forceinline__ GT prep_gt(const float* __restrict__ p) {
  const float cz=p[0], cy=p[1], cx=p[2], sz=p[3], sy=p[4], sx=p[5], label=p[6];
  const bool has_box = label > -1.0f;
  const float loz = fmaxf(cz - sz*0.5f, 0.0f);
  const float loy = fmaxf(cy - sy*0.5f, 0.0f);
  const float lox = fmaxf(cx - sx*0.5f, 0.0f);
  const float hiz = fminf(cz + sz*0.5f, 96.0f);
  const float hiy = fminf(cy + sy*0.5f, 192.0f);
  const float hix = fminf(cx + sx*0.5f, 192.0f);
  const float nz = fmaxf(hiz - loz, 0.0f);
  const float ny = fmaxf(hiy - loy, 0.0f);
  const float nx = fmaxf(hix - lox, 0.0f);
  const float vol = nz * ny * nx;
  const float percent = vol / (sz * sy * sx);
  const bool good = (percent > 0.1f) && (vol >= 15.0f);
  const bool keep = has_box && (vol > 0.0f) && good;
  const bool rejected = has_box && (vol > 0.0f) && !good;
  GT g;
  const float ncz = loz + nz*0.5f, ncy = loy + ny*0.5f, ncx = lox + nx*0.5f;
  if (keep) {
    g.ctr[0]=ncz*0.25f; g.ctr[1]=ncy*0.25f; g.ctr[2]=ncx*0.25f;
    g.half_[0]=nz*0.5f; g.half_[1]=ny*0.5f; g.half_[2]=nx*0.5f;
    g.bbox[0]=ncz; g.bbox[1]=ncy; g.bbox[2]=ncx;
    g.bbox[3]=nz;  g.bbox[4]=ny;  g.bbox[5]=nx;
  } else {
    for (int j=0;j<3;++j){ g.ctr[j]=-0.25f; g.half_[j]=-0.5f; }
    for (int j=0;j<6;++j) g.bbox[j]=-1.0f;
  }
  g.lo[0]=loz; g.lo[1]=loy; g.lo[2]=lox;
  g.hi[0]=hiz; g.hi[1]=hiy; g.hi[2]=hix;
  g.keep = keep ? 1 : 0;
  g.rejected = rejected ? 1 : 0;
  return g;
}

__device__ __forceinline__ int blockReduceSumI(int v) {
  __shared__ int s[4];
  for (int off = 32; off; off >>= 1) v += __shfl_down(v, off, 64);
  if ((threadIdx.x & 63) == 0) s[threadIdx.x >> 6] = v;
  __syncthreads();
  int r = s[0] + s[1] + s[2] + s[3];
  __syncthreads();
  return r;
}
__device__ __forceinline__ float blockReduceSumF(float v) {
  __shared__ float s[4];
  for (int off = 32; off; off >>= 1) v += __shfl_down(v, off, 64);
  if ((threadIdx.x & 63) == 0) s[threadIdx.x >> 6] = v;
  __syncthreads();
  float r = s[0] + s[1] + s[2] + s[3];
  __syncthreads();
  return r;
}

// 256-thread suffix-find over nbins (1024 or 2048) LDS bins.
__device__ void suffix_find_256(const int* h, int nbins, int kt,
                                int* s_bin, int* s_cnt) {
  const int tid = threadIdx.x, lane = tid & 63, wave = tid >> 6;
  const int C = nbins >> 8;
  int csum = 0;
  for (int i = 0; i < C; ++i) csum += h[tid*C + i];
  __shared__ int wts[4];
  int S = csum;
  #pragma unroll
  for (int off = 1; off < 64; off <<= 1) {
    const int t = __shfl_down(S, off, 64);
    if (lane + off < 64) S += t;
  }
  if (lane == 0) wts[wave] = S;
  __syncthreads();
  int above = 0;
  for (int w = wave + 1; w < 4; ++w) above += wts[w];
  const int sfx = above + (S - csum);
  if (sfx < kt && sfx + csum >= kt) {
    int run = sfx;
    for (int i = C - 1; i >= 0; --i) {
      const int c = h[tid*C + i];
      if (run + c >= kt) { *s_bin = tid*C + i; *s_cnt = run; break; }
      run += c;
    }
  }
  __syncthreads();
}

// ---------- D1: per-GT top-7 / top-189 (128 blocks) + embedded init ----------
__global__ __launch_bounds__(256) void k2_topk(const float* __restrict__ ann,
                                               int* __restrict__ plist,
                                               int* __restrict__ ilist,
                                               int* __restrict__ ghist,
                                               Accum* acc) {
  const int bn = blockIdx.x;
  const int tid = threadIdx.x;
  // embedded init: ghist (128 blocks x 256 = BB*NB1 exactly), acc, list prefills
  ghist[bn*256 + tid] = 0;
  if (bn == 0) for (int i = tid; i < (int)(sizeof(Accum)/4); i += 256) ((int*)acc)[i] = 0;
  if (tid < TOPKc) plist[bn*TOPKc + tid] = -1;
  if (tid < NIGN) ilist[bn*NIGN + tid] = -1;

  const GT g = prep_gt(ann + bn*7);
  if (!g.keep) return;
  const float cz = g.ctr[0], cy = g.ctr[1], cx = g.ctr[2];
  const int rz = (int)floorf(cz + 0.5f);
  const int ry = (int)floorf(cy + 0.5f);
  const int rx = (int)floorf(cx + 0.5f);
  const int zlo = min(max(rz - 6, 0),  DD - WZC);
  const int ylo = min(max(ry - 12, 0), HH - WYC);
  const int xlo = min(max(rx - 12, 0), WW - WXC);

  __shared__ int h[1024];
  #pragma unroll
  for (int i = 0; i < 4; ++i) h[tid + i*256] = 0;
  __syncthreads();

#define K2_KEYAID(J, KEY, AID, VALID)                                   \
  const int ci = tid + (J)*256;                                         \
  const bool VALID = ci < CNTC;                                         \
  const int wz = ci / WYXC;                                             \
  const int rem = ci - wz*WYXC;                                         \
  const int wy = rem / WXC;                                             \
  const int wx = rem - wy*WXC;                                          \
  const int z = zlo + wz, y = ylo + wy, x = xlo + wx;                   \
  const float dz = (cz - (float)z) * 2.0f;                              \
  const float dy = cy - (float)y;                                       \
  const float dx = cx - (float)x;                                      \
  const unsigned KEY = fkey(-__builtin_fmaf(dz, dz, __builtin_fmaf(dy, dy, dx*dx))); \
  const int AID = (z*HH + y)*WW + x;

  // pass A: 1024-bin histogram of key>>21
  #pragma unroll
  for (int j = 0; j < CPT; ++j) {
    K2_KEYAID(j, key, aid, valid)
    (void)aid;
    if (valid) atomicAdd(&h[key >> 21], 1);
  }
  __syncthreads();

  // suffix scan: crossing bins for rank 7 and rank 189
  __shared__ int wt[4];
  __shared__ int sB7, sA7, sB9, sA9;
  const int lane = tid & 63, wave = tid >> 6;
  int csum = 0;
  #pragma unroll
  for (int i = 0; i < 4; ++i) csum += h[tid*4 + i];
  int Ssc = csum;
  #pragma unroll
  for (int off = 1; off < 64; off <<= 1) {
    const int t = __shfl_down(Ssc, off, 64);
    if (lane + off < 64) Ssc += t;
  }
  if (lane == 0) wt[wave] = Ssc;
  __syncthreads();
  int above = 0;
  for (int w = wave + 1; w < 4; ++w) above += wt[w];
  const int sfx = above + (Ssc - csum);
  if (sfx < TOPKc && sfx + csum >= TOPKc) {
    int run = sfx;
    for (int i = 3; i >= 0; --i) {
      const int c = h[tid*4 + i];
      if (run + c >= TOPKc) { sB7 = tid*4 + i; sA7 = run; break; }
      run += c;
    }
  }
  if (sfx < KIGN && sfx + csum >= KIGN) {
    int run = sfx;
    for (int i = 3; i >= 0; --i) {
      const int c = h[tid*4 + i];
      if (run + c >= KIGN) { sB9 = tid*4 + i; sA9 = run; break; }
      run += c;
    }
  }
  __syncthreads();
  const int B7 = sB7, A7 = sA7, B9 = sB9, A9 = sA9;

  // pass B: collect keys of crossing bins
  __shared__ unsigned kl7[512], kl9[512];
  __shared__ int n7s, n9s;
  if (tid == 0) { n7s = 0; n9s = 0; }
  __syncthreads();
  #pragma unroll
  for (int j = 0; j < CPT; ++j) {
    K2_KEYAID(j, key, aid, valid)
    (void)aid;
    if (valid) {
      const int bin = (int)(key >> 21);
      if (bin == B7) { const int p = atomicAdd(&n7s, 1); if (p < 512) kl7[p] = key; }
      if (bin == B9 && B9 != B7) { const int p = atomicAdd(&n9s, 1); if (p < 512) kl9[p] = key; }
    }
  }
  __syncthreads();

  // exact k-th key within crossing bin
  __shared__ unsigned sk7, sk9;
  __shared__ int scg7, scg9;
  const int T7c = min(n7s, 512), T9c = min(n9s, 512);
  for (int i = tid; i < T7c; i += 256) {
    const unsigned xv = kl7[i];
    int gt = 0, eq = 0;
    for (int j2 = 0; j2 < T7c; ++j2) { gt += (kl7[j2] > xv); eq += (kl7[j2] == xv); }
    if (A7 + gt < TOPKc && TOPKc <= A7 + gt + eq) { sk7 = xv; scg7 = A7 + gt; }
    if (B9 == B7 && A7 + gt < KIGN && KIGN <= A7 + gt + eq) { sk9 = xv; scg9 = A7 + gt; }
  }
  if (B9 != B7) {
    for (int i = tid; i < T9c; i += 256) {
      const unsigned xv = kl9[i];
      int gt = 0, eq = 0;
      for (int j2 = 0; j2 < T9c; ++j2) { gt += (kl9[j2] > xv); eq += (kl9[j2] == xv); }
      if (A9 + gt < KIGN && KIGN <= A9 + gt + eq) { sk9 = xv; scg9 = A9 + gt; }
    }
  }
  __syncthreads();
  const unsigned k7 = sk7, k9 = sk9;
  const int cg7 = scg7, cg9 = scg9;

  // pass C: boundary-tie anchor lists, index-ranked
  __shared__ int tc7, tc9;
  __shared__ int tl7[256], tr7[256], tl9[256], tr9[256];
  if (tid == 0) { tc7 = 0; tc9 = 0; }
  __syncthreads();
  #pragma unroll
  for (int j = 0; j < CPT; ++j) {
    K2_KEYAID(j, key, aid, valid)
    if (valid) {
      if (key == k7) { const int p = atomicAdd(&tc7, 1); if (p < 256) tl7[p] = aid; }
      if (key == k9 && k9 != k7) { const int p = atomicAdd(&tc9, 1); if (p < 256) tl9[p] = aid; }
    }
  }
  __syncthreads();
  const int T7 = min(tc7, 256), T9 = min(tc9, 256);
  for (int i = tid; i < T7; i += 256) {
    const int ai = tl7[i]; int r = 0;
    for (int j2 = 0; j2 < T7; ++j2) r += (tl7[j2] < ai);
    tr7[i] = r;
  }
  for (int i = tid; i < T9; i += 256) {
    const int ai = tl9[i]; int r = 0;
    for (int j2 = 0; j2 < T9; ++j2) r += (tl9[j2] < ai);
    tr9[i] = r;
  }
  __shared__ int pcnt, icnt;
  if (tid == 0) { pcnt = 0; icnt = 0; }
  __syncthreads();

  // pass D: mark (top -> plist append; ignore -> ilist append); exclusive slices
  #pragma unroll
  for (int j = 0; j < CPT; ++j) {
    K2_KEYAID(j, key, aid, valid)
    if (valid) {
      bool top = false, igf = false;
      if (key > k7) top = true;
      else if (key == k7) {
        int r = 0;
        for (int t = 0; t < T7; ++t) if (tl7[t] == aid) r = tr7[t];
        const int ov = cg7 + r;
        if (ov < TOPKc) top = true;
        else if (ov < KIGN) igf = true;
      } else if (key > k9) igf = true;
      else if (key == k9) {
        int r = 0;
        for (int t = 0; t < T9; ++t) if (tl9[t] == aid) r = tr9[t];
        if (cg9 + r < KIGN) igf = true;
      }
      if (top) { const int s = atomicAdd(&pcnt, 1); if (s < TOPKc) plist[bn*TOPKc + s] = aid; }
      else if (igf) { const int s = atomicAdd(&icnt, 1); if (s < NIGN) ilist[bn*NIGN + s] = aid; }
    }
  }
#undef K2_KEYAID
}

// ---------- D2: per-anchor losses + level-1 hist (ignore mask from ilist) ----------
__global__ __launch_bounds__(256) void k3_loss(
    const float* __restrict__ cls_out, const float* __restrict__ shape_out,
    const float* __restrict__ offset_out, const float* __restrict__ ann,
    const int* __restrict__ plist, const int* __restrict__ ilist,
    float* __restrict__ neg, int* __restrict__ ghist, Accum* acc) {
  __shared__ GT sg[NN];
  __shared__ int pl[NN*TOPKc];
  __shared__ int h1[NB1];
  __shared__ unsigned ibm[8];   // 256-bit ignore mask for this block's anchors
  const int idx = blockIdx.x * 256 + threadIdx.x;
  const int b = idx / AA;            // AA%256==0 -> block-uniform
  const int a = idx - b * AA;
  const int abase = (blockIdx.x % NSEG) * 256;
  if (threadIdx.x < NN) sg[threadIdx.x] = prep_gt(ann + (b*NN + threadIdx.x)*7);
  if (threadIdx.x < NN*TOPKc) pl[threadIdx.x] = plist[b*NN*TOPKc + threadIdx.x];
  if (threadIdx.x < 8) ibm[threadIdx.x] = 0u;
  #pragma unroll
  for (int i = 0; i < NB1/256; ++i) h1[threadIdx.x + i*256] = 0;
  __syncthreads();
  // rebuild ignore bits: 1456 ids, ~6 per thread, L2-hot
  for (int i = threadIdx.x; i < NN*NIGN; i += 256) {
    const int id = ilist[b*NN*NIGN + i];
    const int rel = id - abase;
    if (rel >= 0 && rel < 256) atomicOr(&ibm[rel >> 5], 1u << (rel & 31));
  }
  __syncthreads();

  const int z = a / (HH*WW);
  const int rr = a - z*(HH*WW);
  const int y = rr / WW;
  const int x = rr - y*WW;

  float gign = 0.0f;
  for (int n = 0; n < NN; ++n) {
    if (!sg[n].rejected) continue;
    if ((float)z >= floorf(sg[n].lo[0]) && (float)z < ceilf(sg[n].hi[0]) &&
        (float)y >= floorf(sg[n].lo[1]) && (float)y < ceilf(sg[n].hi[1]) &&
        (float)x >= floorf(sg[n].lo[2]) && (float)x < ceilf(sg[n].hi[2])) gign = -1.0f;
  }

  int pn = NN;
  #pragma unroll
  for (int j = NN*TOPKc - 1; j >= 0; --j) if (pl[j] == a) pn = j / TOPKc;
  const bool is_pos = (pn < NN);
  const float target = is_pos ? 1.0f : 0.0f;
  const int ibit = (ibm[threadIdx.x >> 5] >> (threadIdx.x & 31)) & 1;
  const float ignore = (ibit ? -1.0f : 0.0f) + gign;
  const float pred = cls_out[idx];
  float prob = 1.0f / (1.0f + expf(-pred));
  prob = fminf(fmaxf(prob, 1e-4f), 1.0f - 1e-4f);
  const float alpha_f = is_pos ? 0.75f : 0.25f;
  const float pt = is_pos ? (1.0f - prob) : prob;
  const float fw = alpha_f * pt * pt;
  const float bce = fmaxf(pred, 0.0f) + log1pf(expf(-fabsf(pred))) - pred * target;
  float loss = (ignore == 0.0f) ? fw * bce : 0.0f;
  if (prob < 0.8f && is_pos) loss *= 4.0f;
  const float nval = is_pos ? -1.0f : loss;
  neg[idx] = nval;

  agg_lds_add(h1, (int)(fkey(nval) >> 21));

  const int np = blockReduceSumI(is_pos ? 1 : 0);
  const float ps = blockReduceSumF(is_pos ? loss : 0.0f);
  if (threadIdx.x == 0 && np) {
    atomicAdd(&acc->npos[b], np);
    atomicAdd(&acc->pos_sum[b], ps);
  }

  if (is_pos) {
    const GT& g = sg[pn];
    const float toz = g.ctr[0] - (float)z;
    const float toy = g.ctr[1] - (float)y;
    const float tox = g.ctr[2] - (float)x;
    const float poz = offset_out[((size_t)b*3 + 0)*AA + a];
    const float poy = offset_out[((size_t)b*3 + 1)*AA + a];
    const float pox = offset_out[((size_t)b*3 + 2)*AA + a];
    const float psz = shape_out[((size_t)b*3 + 0)*AA + a];
    const float psy = shape_out[((size_t)b*3 + 1)*AA + a];
    const float psx = shape_out[((size_t)b*3 + 2)*AA + a];
    const float off_t = fabsf(poz - toz) + fabsf(poy - toy) + fabsf(pox - tox);
    const float shp_t = fabsf(psz - g.half_[0]) + fabsf(psy - g.half_[1]) + fabsf(psx - g.half_[2]);
    const float c1z = ((float)z + poz) * 4.0f;
    const float c1y = ((float)y + poy) * 4.0f;
    const float c1x = ((float)x + pox) * 4.0f;
    const float s1z = 2.0f*psz, s1y = 2.0f*psy, s1x = 2.0f*psx;
    const float lo1z = c1z - s1z*0.5f, hi1z = c1z + s1z*0.5f;
    const float lo1y = c1y - s1y*0.5f, hi1y = c1y + s1y*0.5f;
    const float lo1x = c1x - s1x*0.5f, hi1x = c1x + s1x*0.5f;
    const float c2z = g.bbox[0], c2y = g.bbox[1], c2x = g.bbox[2];
    const float s2z = g.bbox[3], s2y = g.bbox[4], s2x = g.bbox[5];
    const float lo2z = c2z - s2z*0.5f, hi2z = c2z + s2z*0.5f;
    const float lo2y = c2y - s2y*0.5f, hi2y = c2y + s2y*0.5f;
    const float lo2x = c2x - s2x*0.5f, hi2x = c2x + s2x*0.5f;
    const float iz = fmaxf(fminf(hi1z,hi2z) - fmaxf(lo1z,lo2z), 0.0f);
    const float iy = fmaxf(fminf(hi1y,hi2y) - fmaxf(lo1y,lo2y), 0.0f);
    const float ix = fmaxf(fminf(hi1x,hi2x) - fmaxf(lo1x,lo2x), 0.0f);
    const float inter = iz*iy*ix + 1e-7f;
    const float uni = s1z*s1y*s1x + s2z*s2y*s2x - inter;
    const float iou = inter / uni;
    const float ez = fmaxf(hi1z,hi2z) - fminf(lo1z,lo2z);
    const float ey = fmaxf(hi1y,hi2y) - fminf(lo1y,lo2y);
    const float ex = fmaxf(hi1x,hi2x) - fminf(lo1x,lo2x);
    const float c2d = (ez*ez + ey*ey) + ex*ex + 1e-7f;
    const float rz2 = (lo2z + hi2z) - (lo1z + hi1z);
    const float ry2 = (lo2y + hi2y) - (lo1y + hi1y);
    const float rx2 = (lo2x + hi2x) - (lo1x + hi1x);
    const float rho2 = ((rz2*rz2 + ry2*ry2) + rx2*rx2) * 0.25f;
    const float diou = iou - rho2 / c2d;
    atomicAdd(&acc->shape_sum, shp_t);
    atomicAdd(&acc->off_sum, off_t);
    atomicAdd(&acc->iou_sum, diou);
  }

  __syncthreads();
  #pragma unroll
  for (int i = 0; i < NB1/256; ++i) {
    const int bin = threadIdx.x + i*256;
    const int c = h1[bin];
    if (c) atomicAdd(&ghist[b*NB1 + bin], c);
  }
}

// ---------- D3: gather + per-image parallel tails (stream-ordered, no binary search) ----------
__global__ __launch_bounds__(256) void kfinal(const float* __restrict__ neg,
                                              const int* __restrict__ ghist,
                                              float* __restrict__ list,
                                              float* __restrict__ psum,
                                              int* __restrict__ seg_cnt,
                                              Accum* acc, float* __restrict__ out) {
  __shared__ int h[2048];      // levels 2/3 (tail only)
  __shared__ int cnS[NSEG];
  const int bid = blockIdx.x;
  const int tid = threadIdx.x, lane = tid & 63, wave = tid >> 6;
  const int b = bid / NSEG;
  const int seg = bid - b*NSEG;

  // phase 0: recompute this image's B1 from the 2048-bin global hist (L2-hot)
  const int npos = acc->npos[b];
  const int k = npos > 0 ? 100*npos : 100;
  __shared__ int sB1, sCA;
  {
    const int* hb = ghist + b*NB1;
    int hv[8];
    #pragma unroll
    for (int i = 0; i < 8; ++i) hv[i] = hb[tid*8 + i];
    int csum = 0;
    #pragma unroll
    for (int i = 0; i < 8; ++i) csum += hv[i];
    __shared__ int wt[4];
    int S = csum;
    #pragma unroll
    for (int off = 1; off < 64; off <<= 1) {
      const int t = __shfl_down(S, off, 64);
      if (lane + off < 64) S += t;
    }
    if (lane == 0) wt[wave] = S;
    __syncthreads();
    int above = 0;
    for (int w = wave + 1; w < 4; ++w) above += wt[w];
    const int sfx = above + (S - csum);
    if (sfx < k && sfx + csum >= k) {
      int run = sfx;
      for (int i = 7; i >= 0; --i) {
        if (run + hv[i] >= k) { sB1 = tid*8 + i; sCA = run; break; }
        run += hv[i];
      }
    }
    __syncthreads();
  }
  const int B1 = sB1, cnt_above = sCA;

  // phase 1: partial sum above-B1 (nonneg only) + segment-local compaction
  const int idx = b*AA + seg*256 + tid;
  const float val = neg[idx];
  const int bin = (int)(fkey(val) >> 21);
  const float aval = (bin > B1 && bin >= 1024) ? val : 0.0f;
  const float bs = blockReduceSumF(aval);

  const bool match = (bin == B1);
  const unsigned long long mask = __ballot(match);
  __shared__ int wc[4];
  if (lane == 0) wc[wave] = (int)__popcll(mask);
  __syncthreads();
  int wbase = 0;
  for (int w = 0; w < wave; ++w) wbase += wc[w];
  if (match) {
    const int pos = (int)__popcll(mask & ((1ull << lane) - 1ull));
    list[(size_t)b*AA + seg*256 + wbase + pos] = val;
  }
  if (tid == 0) {
    psum[bid] = bs;
    seg_cnt[bid] = wc[0] + wc[1] + wc[2] + wc[3];
  }

  // release; last block of this image becomes its selection tail
  __threadfence();
  __shared__ int lastSeg;
  if (tid == 0) lastSeg = (atomicAdd(&acc->done_img[b*32], 1) == NSEG - 1) ? 1 : 0;
  __syncthreads();
  if (!lastSeg) return;
  __threadfence();   // acquire: all 216 segments' stores visible

  // ---- per-image selection (256 threads, stream-ordered passes) ----
  float pv = 0.0f;
  for (int i = tid; i < NSEG; i += 256) pv += psum[b*NSEG + i];
  const float sum_above = blockReduceSumF(pv);
  const float pos_sum = acc->pos_sum[b];

  if (B1 < 1024) {   // k-th value negative: only nonneg values counted
    if (tid == 0) acc->per_img[b] = (pos_sum + sum_above) / fmaxf((float)npos, 1.0f);
  } else {
    if (tid < NSEG) cnS[tid] = seg_cnt[b*NSEG + tid];
    #pragma unroll
    for (int i = 0; i < 8; ++i) h[tid + i*256] = 0;
    __syncthreads();
    const int kt2 = k - cnt_above;   // >= 1
    const float* lb = list + (size_t)b*AA;
    __shared__ int sB2, sC2, sB3, sC3;

    // pass 1: level-2 hist (key bits 20..10); coalesced, pipelined loads
    for (int s = 0; s < NSEG; ++s) {
      const int c = cnS[s];
      if (tid < c) {
        const float v = lb[s*256 + tid];
        atomicAdd(&h[(fkey(v) >> 10) & 0x7FF], 1);
      }
    }
    __syncthreads();
    suffix_find_256(h, 2048, kt2, &sB2, &sC2);
    const int B2 = sB2;
    const int kt3 = kt2 - sC2;       // >= 1
    #pragma unroll
    for (int i = 0; i < 4; ++i) h[tid + i*256] = 0;
    __syncthreads();

    // pass 2: msum/mcnt for sub > B2; level-3 hist for sub == B2
    float msum = 0.0f; int mcnt = 0;
    for (int s = 0; s < NSEG; ++s) {
      const int c = cnS[s];
      if (tid < c) {
        const float v = lb[s*256 + tid];
        const unsigned key = fkey(v);
        const int sub = (int)((key >> 10) & 0x7FF);
        if (sub > B2) { msum += v; mcnt++; }
        else if (sub == B2) atomicAdd(&h[key & 0x3FF], 1);
      }
    }
    __syncthreads();
    suffix_find_256(h, 1024, kt3, &sB3, &sC3);
    const int B3 = sB3;
    const unsigned Kstar = ((unsigned)B1 << 21) | ((unsigned)B2 << 10) | (unsigned)B3;
    const float vK = fkey_inv(Kstar);  // >= 0 since B1 >= 1024

    // pass 3: count/sum of sub == B2 with low bits > B3
    for (int s = 0; s < NSEG; ++s) {
      const int c = cnS[s];
      if (tid < c) {
        const float x = lb[s*256 + tid];
        const unsigned key = fkey(x);
        if ((int)((key >> 10) & 0x7FF) == B2 && (int)(key & 0x3FF) > B3) { msum += x; mcnt++; }
      }
    }
    const int cg = blockReduceSumI(mcnt);
    const float sg = blockReduceSumF(msum);
    if (tid == 0) {
      const int total_gt = cnt_above + cg;
      const float ns = sum_above + sg + (float)(k - total_gt) * vK;
      acc->per_img[b] = (pos_sum + ns) / fmaxf((float)npos, 1.0f);
    }
  }

  // final: last of the 16 image-tails writes out[0..3]
  __threadfence();
  __shared__ int lastAll;
  if (tid == 0) lastAll = (atomicAdd(&acc->done, 1) == BB - 1) ? 1 : 0;
  __syncthreads();
  if (!lastAll) return;
  __threadfence();
  if (tid == 0) {
    float s = 0.0f; int tot = 0;
    for (int b2 = 0; b2 < BB; ++b2) { s += acc->per_img[b2]; tot += acc->npos[b2]; }
    out[0] = s / (float)BB;
    const float denom = fmaxf((float)tot, 1.0f);
    out[1] = acc->shape_sum / (denom * 3.0f);
    out[2] = acc->off_sum / (denom * 3.0f);
    out[3] = 1.0f - acc->iou_sum / denom;
  }
}

extern "C" void kernel_launch(void* const* d_in, const int* in_sizes, int n_in,
                              void* d_out, int out_size, void* d_ws, size_t ws_size,
                              hipStream_t stream) {
  const float* cls_out    = (const float*)d_in[0];
  const float* shape_out  = (const float*)d_in[1];
  const float* offset_out = (const float*)d_in[2];
  const float* ann        = (const float*)d_in[3];
  float* out = (float*)d_out;

  char* ws = (char*)d_ws;
  Accum* acc    = (Accum*)ws;                               // ~2.4 KB
  int* plist    = (int*)(ws + 4096);                        // 128*7   = 3.6 KB
  int* ilist    = plist + (size_t)BB*NN*TOPKc;              // 128*182 = 93 KB
  int* ghist    = ilist + (size_t)BB*NN*NIGN;               // 32768   = 128 KB
  float* neg    = (float*)(ghist + (size_t)BB*NB1);         // 3.54 MB
  float* list   = neg + (size_t)BB*AA;                      // 3.54 MB
  float* psum   = list + (size_t)BB*AA;                     // 13.8 KB
  int* seg_cnt  = (int*)(psum + (size_t)BB*NSEG);           // 13.8 KB

  hipLaunchKernelGGL(k2_topk, dim3(BB*NN), dim3(256), 0, stream,
                     ann, plist, ilist, ghist, acc);
  hipLaunchKernelGGL(k3_loss, dim3(NBLK), dim3(256), 0, stream,
                     cls_out, shape_out, offset_out, ann, plist, ilist, neg, ghist, acc);
  hipLaunchKernelGGL(kfinal, dim3(NBLK), dim3(256), 0, stream,
                     neg, ghist, list, psum, seg_cnt, acc, out);
}

// Round 13
// 105.581 us; speedup vs baseline: 4.5795x; 4.5795x over previous
//
#include <hip/hip_runtime.h>

#define BB 16
#define NN 8
#define DD 24
#define HH 48
#define WW 48
#define AA (DD*HH*WW)   // 55296
#define NSEG (AA/256)   // 216 segments per image
#define NBLK ((BB*AA)/256)  // 3456
#define TOPKc 7
#define KIGN 189        // (IGNORE_RATIO+1)*TOPK
#define NIGN 182        // exactly KIGN-TOPKc ignore marks per kept GT
#define NB1 2048        // level-1 bins = key >> 21

// fixed candidate window (shifted to stay in-grid): 13 x 25 x 25 = 8125
#define WZC 13
#define WYC 25
#define WXC 25
#define WYXC (WYC*WXC)          // 625
#define CNTC (WZC*WYXC)         // 8125
#define CPT 32                  // 32*256 = 8192 >= 8125

struct GT {
  float ctr[3];
  float half_[3];
  float bbox[6];
  float lo[3], hi[3];
  int keep, rejected;
};

struct Accum {
  int   npos[BB];
  float pos_sum[BB];
  float shape_sum, off_sum, iou_sum;
  float per_img[BB];
  int   B1[BB];
  int   cnt_above[BB];
  int   done;             // ksel image-tail done counter (16 blocks only)
};

__device__ __forceinline__ unsigned fkey(float f) {
  unsigned u = __float_as_uint(f);
  return (u & 0x80000000u) ? ~u : (u | 0x80000000u);
}
__device__ __forceinline__ float fkey_inv(unsigned k) {
  return __uint_as_float((k & 0x80000000u) ? (k & 0x7FFFFFFFu) : ~k);
}

// Wave-aggregated LDS histogram add (for heavily SKEWED bins, e.g. k3 level-1).
__device__ __forceinline__ void agg_lds_add(int* h, int bin) {
  const int lane = threadIdx.x & 63;
  unsigned long long todo = __ballot(bin >= 0);
  while (todo) {
    const int leader = __ffsll((unsigned long long)todo) - 1;
    const int lbin = __shfl(bin, leader, 64);
    const unsigned long long eq = __ballot(bin == lbin) & todo;
    if (lane == leader) atomicAdd(&h[lbin], (int)__popcll(eq));
    todo &= ~eq;
  }
}

__device__ __forceinline__ GT prep_gt(const float* __restrict__ p) {
  const float cz=p[0], cy=p[1], cx=p[2], sz=p[3], sy=p[4], sx=p[5], label=p[6];
  const bool has_box = label > -1.0f;
  const float loz = fmaxf(cz - sz*0.5f, 0.0f);
  const float loy = fmaxf(cy - sy*0.5f, 0.0f);
  const float lox = fmaxf(cx - sx*0.5f, 0.0f);
  const float hiz = fminf(cz + sz*0.5f, 96.0f);
  const float hiy = fminf(cy + sy*0.5f, 192.0f);
  const float hix = fminf(cx + sx*0.5f, 192.0f);
  const float nz = fmaxf(hiz - loz, 0.0f);
  const float ny = fmaxf(hiy - loy, 0.0f);
  const float nx = fmaxf(hix - lox, 0.0f);
  const float vol = nz * ny * nx;
  const float percent = vol / (sz * sy * sx);
  const bool good = (percent > 0.1f) && (vol >= 15.0f);
  const bool keep = has_box && (vol > 0.0f) && good;
  const bool rejected = has_box && (vol > 0.0f) && !good;
  GT g;
  const float ncz = loz + nz*0.5f, ncy = loy + ny*0.5f, ncx = lox + nx*0.5f;
  if (keep) {
    g.ctr[0]=ncz*0.25f; g.ctr[1]=ncy*0.25f; g.ctr[2]=ncx*0.25f;
    g.half_[0]=nz*0.5f; g.half_[1]=ny*0.5f; g.half_[2]=nx*0.5f;
    g.bbox[0]=ncz; g.bbox[1]=ncy; g.bbox[2]=ncx;
    g.bbox[3]=nz;  g.bbox[4]=ny;  g.bbox[5]=nx;
  } else {
    for (int j=0;j<3;++j){ g.ctr[j]=-0.25f; g.half_[j]=-0.5f; }
    for (int j=0;j<6;++j) g.bbox[j]=-1.0f;
  }
  g.lo[0]=loz; g.lo[1]=loy; g.lo[2]=lox;
  g.hi[0]=hiz; g.hi[1]=hiy; g.hi[2]=hix;
  g.keep = keep ? 1 : 0;
  g.rejected = rejected ? 1 : 0;
  return g;
}

__device__ __forceinline__ int blockReduceSumI(int v) {
  __shared__ int s[4];
  for (int off = 32; off; off >>= 1) v += __shfl_down(v, off, 64);
  if ((threadIdx.x & 63) == 0) s[threadIdx.x >> 6] = v;
  __syncthreads();
  int r = s[0] + s[1] + s[2] + s[3];
  __syncthreads();
  return r;
}
__device__ __forceinline__ float blockReduceSumF(float v) {
  __shared__ float s[4];
  for (int off = 32; off; off >>= 1) v += __shfl_down(v, off, 64);
  if ((threadIdx.x & 63) == 0) s[threadIdx.x >> 6] = v;
  __syncthreads();
  float r = s[0] + s[1] + s[2] + s[3];
  __syncthreads();
  return r;
}
__device__ __forceinline__ int redI1024(int v) {
  __shared__ int s[16];
  for (int off = 32; off; off >>= 1) v += __shfl_down(v, off, 64);
  if ((threadIdx.x & 63) == 0) s[threadIdx.x >> 6] = v;
  __syncthreads();
  int r = 0;
  #pragma unroll
  for (int w = 0; w < 16; ++w) r += s[w];
  __syncthreads();
  return r;
}
__device__ __forceinline__ float redF1024(float v) {
  __shared__ float s[16];
  for (int off = 32; off; off >>= 1) v += __shfl_down(v, off, 64);
  if ((threadIdx.x & 63) == 0) s[threadIdx.x >> 6] = v;
  __syncthreads();
  float r = 0.0f;
  #pragma unroll
  for (int w = 0; w < 16; ++w) r += s[w];
  __syncthreads();
  return r;
}

// 1024-thread suffix-find over nbins (1024 or 2048) LDS bins.
__device__ void suffix_find_1024(const int* h, int nbins, int ktarget,
                                 int* s_bin, int* s_cnt) {
  const int tid = threadIdx.x, lane = tid & 63, wave = tid >> 6;
  const int C = nbins >> 10;
  int csum = 0;
  for (int i = 0; i < C; ++i) csum += h[tid*C + i];
  __shared__ int wt[16];
  int S = csum;
  #pragma unroll
  for (int off = 1; off < 64; off <<= 1) {
    const int t = __shfl_down(S, off, 64);
    if (lane + off < 64) S += t;
  }
  if (lane == 0) wt[wave] = S;
  __syncthreads();
  int above = 0;
  for (int w = wave + 1; w < 16; ++w) above += wt[w];
  const int sfx = above + (S - csum);
  if (sfx < ktarget && sfx + csum >= ktarget) {
    int running = sfx;
    for (int i = C - 1; i >= 0; --i) {
      const int c = h[tid*C + i];
      if (running + c >= ktarget) { *s_bin = tid*C + i; *s_cnt = running; break; }
      running += c;
    }
  }
  __syncthreads();
}

// ---------- D1: per-GT top-7 / top-189 (128 blocks) + embedded init ----------
__global__ __launch_bounds__(256) void k2_topk(const float* __restrict__ ann,
                                               int* __restrict__ plist,
                                               int* __restrict__ ilist,
                                               int* __restrict__ ghist,
                                               Accum* acc) {
  const int bn = blockIdx.x;
  const int tid = threadIdx.x;
  // embedded init: ghist (128 blocks x 256 = BB*NB1 exactly), acc, list prefills
  ghist[bn*256 + tid] = 0;
  if (bn == 0) for (int i = tid; i < (int)(sizeof(Accum)/4); i += 256) ((int*)acc)[i] = 0;
  if (tid < TOPKc) plist[bn*TOPKc + tid] = -1;
  if (tid < NIGN) ilist[bn*NIGN + tid] = -1;

  const GT g = prep_gt(ann + bn*7);
  if (!g.keep) return;
  const float cz = g.ctr[0], cy = g.ctr[1], cx = g.ctr[2];
  const int rz = (int)floorf(cz + 0.5f);
  const int ry = (int)floorf(cy + 0.5f);
  const int rx = (int)floorf(cx + 0.5f);
  const int zlo = min(max(rz - 6, 0),  DD - WZC);
  const int ylo = min(max(ry - 12, 0), HH - WYC);
  const int xlo = min(max(rx - 12, 0), WW - WXC);

  __shared__ int h[1024];
  #pragma unroll
  for (int i = 0; i < 4; ++i) h[tid + i*256] = 0;
  __syncthreads();

#define K2_KEYAID(J, KEY, AID, VALID)                                   \
  const int ci = tid + (J)*256;                                         \
  const bool VALID = ci < CNTC;                                         \
  const int wz = ci / WYXC;                                             \
  const int rem = ci - wz*WYXC;                                         \
  const int wy = rem / WXC;                                             \
  const int wx = rem - wy*WXC;                                          \
  const int z = zlo + wz, y = ylo + wy, x = xlo + wx;                   \
  const float dz = (cz - (float)z) * 2.0f;                              \
  const float dy = cy - (float)y;                                       \
  const float dx = cx - (float)x;                                      \
  const unsigned KEY = fkey(-__builtin_fmaf(dz, dz, __builtin_fmaf(dy, dy, dx*dx))); \
  const int AID = (z*HH + y)*WW + x;

  // pass A: 1024-bin histogram of key>>21
  #pragma unroll
  for (int j = 0; j < CPT; ++j) {
    K2_KEYAID(j, key, aid, valid)
    (void)aid;
    if (valid) atomicAdd(&h[key >> 21], 1);
  }
  __syncthreads();

  // suffix scan: crossing bins for rank 7 and rank 189
  __shared__ int wt[4];
  __shared__ int sB7, sA7, sB9, sA9;
  const int lane = tid & 63, wave = tid >> 6;
  int csum = 0;
  #pragma unroll
  for (int i = 0; i < 4; ++i) csum += h[tid*4 + i];
  int Ssc = csum;
  #pragma unroll
  for (int off = 1; off < 64; off <<= 1) {
    const int t = __shfl_down(Ssc, off, 64);
    if (lane + off < 64) Ssc += t;
  }
  if (lane == 0) wt[wave] = Ssc;
  __syncthreads();
  int above = 0;
  for (int w = wave + 1; w < 4; ++w) above += wt[w];
  const int sfx = above + (Ssc - csum);
  if (sfx < TOPKc && sfx + csum >= TOPKc) {
    int run = sfx;
    for (int i = 3; i >= 0; --i) {
      const int c = h[tid*4 + i];
      if (run + c >= TOPKc) { sB7 = tid*4 + i; sA7 = run; break; }
      run += c;
    }
  }
  if (sfx < KIGN && sfx + csum >= KIGN) {
    int run = sfx;
    for (int i = 3; i >= 0; --i) {
      const int c = h[tid*4 + i];
      if (run + c >= KIGN) { sB9 = tid*4 + i; sA9 = run; break; }
      run += c;
    }
  }
  __syncthreads();
  const int B7 = sB7, A7 = sA7, B9 = sB9, A9 = sA9;

  // pass B: collect keys of crossing bins
  __shared__ unsigned kl7[512], kl9[512];
  __shared__ int n7s, n9s;
  if (tid == 0) { n7s = 0; n9s = 0; }
  __syncthreads();
  #pragma unroll
  for (int j = 0; j < CPT; ++j) {
    K2_KEYAID(j, key, aid, valid)
    (void)aid;
    if (valid) {
      const int bin = (int)(key >> 21);
      if (bin == B7) { const int p = atomicAdd(&n7s, 1); if (p < 512) kl7[p] = key; }
      if (bin == B9 && B9 != B7) { const int p = atomicAdd(&n9s, 1); if (p < 512) kl9[p] = key; }
    }
  }
  __syncthreads();

  // exact k-th key within crossing bin
  __shared__ unsigned sk7, sk9;
  __shared__ int scg7, scg9;
  const int T7c = min(n7s, 512), T9c = min(n9s, 512);
  for (int i = tid; i < T7c; i += 256) {
    const unsigned xv = kl7[i];
    int gt = 0, eq = 0;
    for (int j2 = 0; j2 < T7c; ++j2) { gt += (kl7[j2] > xv); eq += (kl7[j2] == xv); }
    if (A7 + gt < TOPKc && TOPKc <= A7 + gt + eq) { sk7 = xv; scg7 = A7 + gt; }
    if (B9 == B7 && A7 + gt < KIGN && KIGN <= A7 + gt + eq) { sk9 = xv; scg9 = A7 + gt; }
  }
  if (B9 != B7) {
    for (int i = tid; i < T9c; i += 256) {
      const unsigned xv = kl9[i];
      int gt = 0, eq = 0;
      for (int j2 = 0; j2 < T9c; ++j2) { gt += (kl9[j2] > xv); eq += (kl9[j2] == xv); }
      if (A9 + gt < KIGN && KIGN <= A9 + gt + eq) { sk9 = xv; scg9 = A9 + gt; }
    }
  }
  __syncthreads();
  const unsigned k7 = sk7, k9 = sk9;
  const int cg7 = scg7, cg9 = scg9;

  // pass C: boundary-tie anchor lists, index-ranked
  __shared__ int tc7, tc9;
  __shared__ int tl7[256], tr7[256], tl9[256], tr9[256];
  if (tid == 0) { tc7 = 0; tc9 = 0; }
  __syncthreads();
  #pragma unroll
  for (int j = 0; j < CPT; ++j) {
    K2_KEYAID(j, key, aid, valid)
    if (valid) {
      if (key == k7) { const int p = atomicAdd(&tc7, 1); if (p < 256) tl7[p] = aid; }
      if (key == k9 && k9 != k7) { const int p = atomicAdd(&tc9, 1); if (p < 256) tl9[p] = aid; }
    }
  }
  __syncthreads();
  const int T7 = min(tc7, 256), T9 = min(tc9, 256);
  for (int i = tid; i < T7; i += 256) {
    const int ai = tl7[i]; int r = 0;
    for (int j2 = 0; j2 < T7; ++j2) r += (tl7[j2] < ai);
    tr7[i] = r;
  }
  for (int i = tid; i < T9; i += 256) {
    const int ai = tl9[i]; int r = 0;
    for (int j2 = 0; j2 < T9; ++j2) r += (tl9[j2] < ai);
    tr9[i] = r;
  }
  __shared__ int pcnt, icnt;
  if (tid == 0) { pcnt = 0; icnt = 0; }
  __syncthreads();

  // pass D: mark (top -> plist append; ignore -> ilist append); exclusive slices
  #pragma unroll
  for (int j = 0; j < CPT; ++j) {
    K2_KEYAID(j, key, aid, valid)
    if (valid) {
      bool top = false, igf = false;
      if (key > k7) top = true;
      else if (key == k7) {
        int r = 0;
        for (int t = 0; t < T7; ++t) if (tl7[t] == aid) r = tr7[t];
        const int ov = cg7 + r;
        if (ov < TOPKc) top = true;
        else if (ov < KIGN) igf = true;
      } else if (key > k9) igf = true;
      else if (key == k9) {
        int r = 0;
        for (int t = 0; t < T9; ++t) if (tl9[t] == aid) r = tr9[t];
        if (cg9 + r < KIGN) igf = true;
      }
      if (top) { const int s = atomicAdd(&pcnt, 1); if (s < TOPKc) plist[bn*TOPKc + s] = aid; }
      else if (igf) { const int s = atomicAdd(&icnt, 1); if (s < NIGN) ilist[bn*NIGN + s] = aid; }
    }
  }
#undef K2_KEYAID
}

// ---------- D2: per-anchor losses + level-1 hist (ignore mask from ilist) ----------
__global__ __launch_bounds__(256) void k3_loss(
    const float* __restrict__ cls_out, const float* __restrict__ shape_out,
    const float* __restrict__ offset_out, const float* __restrict__ ann,
    const int* __restrict__ plist, const int* __restrict__ ilist,
    float* __restrict__ neg, int* __restrict__ ghist, Accum* acc) {
  __shared__ GT sg[NN];
  __shared__ int pl[NN*TOPKc];
  __shared__ int h1[NB1];
  __shared__ unsigned ibm[8];   // 256-bit ignore mask for this block's anchors
  const int idx = blockIdx.x * 256 + threadIdx.x;
  const int b = idx / AA;            // AA%256==0 -> block-uniform
  const int a = idx - b * AA;
  const int abase = (blockIdx.x % NSEG) * 256;
  if (threadIdx.x < NN) sg[threadIdx.x] = prep_gt(ann + (b*NN + threadIdx.x)*7);
  if (threadIdx.x < NN*TOPKc) pl[threadIdx.x] = plist[b*NN*TOPKc + threadIdx.x];
  if (threadIdx.x < 8) ibm[threadIdx.x] = 0u;
  #pragma unroll
  for (int i = 0; i < NB1/256; ++i) h1[threadIdx.x + i*256] = 0;
  __syncthreads();
  // rebuild ignore bits: 1456 ids, ~6 per thread, L2-hot
  for (int i = threadIdx.x; i < NN*NIGN; i += 256) {
    const int id = ilist[b*NN*NIGN + i];
    const int rel = id - abase;
    if (rel >= 0 && rel < 256) atomicOr(&ibm[rel >> 5], 1u << (rel & 31));
  }
  __syncthreads();

  const int z = a / (HH*WW);
  const int rr = a - z*(HH*WW);
  const int y = rr / WW;
  const int x = rr - y*WW;

  float gign = 0.0f;
  for (int n = 0; n < NN; ++n) {
    if (!sg[n].rejected) continue;
    if ((float)z >= floorf(sg[n].lo[0]) && (float)z < ceilf(sg[n].hi[0]) &&
        (float)y >= floorf(sg[n].lo[1]) && (float)y < ceilf(sg[n].hi[1]) &&
        (float)x >= floorf(sg[n].lo[2]) && (float)x < ceilf(sg[n].hi[2])) gign = -1.0f;
  }

  int pn = NN;
  #pragma unroll
  for (int j = NN*TOPKc - 1; j >= 0; --j) if (pl[j] == a) pn = j / TOPKc;
  const bool is_pos = (pn < NN);
  const float target = is_pos ? 1.0f : 0.0f;
  const int ibit = (ibm[threadIdx.x >> 5] >> (threadIdx.x & 31)) & 1;
  const float ignore = (ibit ? -1.0f : 0.0f) + gign;
  const float pred = cls_out[idx];
  float prob = 1.0f / (1.0f + expf(-pred));
  prob = fminf(fmaxf(prob, 1e-4f), 1.0f - 1e-4f);
  const float alpha_f = is_pos ? 0.75f : 0.25f;
  const float pt = is_pos ? (1.0f - prob) : prob;
  const float fw = alpha_f * pt * pt;
  const float bce = fmaxf(pred, 0.0f) + log1pf(expf(-fabsf(pred))) - pred * target;
  float loss = (ignore == 0.0f) ? fw * bce : 0.0f;
  if (prob < 0.8f && is_pos) loss *= 4.0f;
  const float nval = is_pos ? -1.0f : loss;
  neg[idx] = nval;

  agg_lds_add(h1, (int)(fkey(nval) >> 21));

  const int np = blockReduceSumI(is_pos ? 1 : 0);
  const float ps = blockReduceSumF(is_pos ? loss : 0.0f);
  if (threadIdx.x == 0 && np) {
    atomicAdd(&acc->npos[b], np);
    atomicAdd(&acc->pos_sum[b], ps);
  }

  if (is_pos) {
    const GT& g = sg[pn];
    const float toz = g.ctr[0] - (float)z;
    const float toy = g.ctr[1] - (float)y;
    const float tox = g.ctr[2] - (float)x;
    const float poz = offset_out[((size_t)b*3 + 0)*AA + a];
    const float poy = offset_out[((size_t)b*3 + 1)*AA + a];
    const float pox = offset_out[((size_t)b*3 + 2)*AA + a];
    const float psz = shape_out[((size_t)b*3 + 0)*AA + a];
    const float psy = shape_out[((size_t)b*3 + 1)*AA + a];
    const float psx = shape_out[((size_t)b*3 + 2)*AA + a];
    const float off_t = fabsf(poz - toz) + fabsf(poy - toy) + fabsf(pox - tox);
    const float shp_t = fabsf(psz - g.half_[0]) + fabsf(psy - g.half_[1]) + fabsf(psx - g.half_[2]);
    const float c1z = ((float)z + poz) * 4.0f;
    const float c1y = ((float)y + poy) * 4.0f;
    const float c1x = ((float)x + pox) * 4.0f;
    const float s1z = 2.0f*psz, s1y = 2.0f*psy, s1x = 2.0f*psx;
    const float lo1z = c1z - s1z*0.5f, hi1z = c1z + s1z*0.5f;
    const float lo1y = c1y - s1y*0.5f, hi1y = c1y + s1y*0.5f;
    const float lo1x = c1x - s1x*0.5f, hi1x = c1x + s1x*0.5f;
    const float c2z = g.bbox[0], c2y = g.bbox[1], c2x = g.bbox[2];
    const float s2z = g.bbox[3], s2y = g.bbox[4], s2x = g.bbox[5];
    const float lo2z = c2z - s2z*0.5f, hi2z = c2z + s2z*0.5f;
    const float lo2y = c2y - s2y*0.5f, hi2y = c2y + s2y*0.5f;
    const float lo2x = c2x - s2x*0.5f, hi2x = c2x + s2x*0.5f;
    const float iz = fmaxf(fminf(hi1z,hi2z) - fmaxf(lo1z,lo2z), 0.0f);
    const float iy = fmaxf(fminf(hi1y,hi2y) - fmaxf(lo1y,lo2y), 0.0f);
    const float ix = fmaxf(fminf(hi1x,hi2x) - fmaxf(lo1x,lo2x), 0.0f);
    const float inter = iz*iy*ix + 1e-7f;
    const float uni = s1z*s1y*s1x + s2z*s2y*s2x - inter;
    const float iou = inter / uni;
    const float ez = fmaxf(hi1z,hi2z) - fminf(lo1z,lo2z);
    const float ey = fmaxf(hi1y,hi2y) - fminf(lo1y,lo2y);
    const float ex = fmaxf(hi1x,hi2x) - fminf(lo1x,lo2x);
    const float c2d = (ez*ez + ey*ey) + ex*ex + 1e-7f;
    const float rz2 = (lo2z + hi2z) - (lo1z + hi1z);
    const float ry2 = (lo2y + hi2y) - (lo1y + hi1y);
    const float rx2 = (lo2x + hi2x) - (lo1x + hi1x);
    const float rho2 = ((rz2*rz2 + ry2*ry2) + rx2*rx2) * 0.25f;
    const float diou = iou - rho2 / c2d;
    atomicAdd(&acc->shape_sum, shp_t);
    atomicAdd(&acc->off_sum, off_t);
    atomicAdd(&acc->iou_sum, diou);
  }

  __syncthreads();
  #pragma unroll
  for (int i = 0; i < NB1/256; ++i) {
    const int bin = threadIdx.x + i*256;
    const int c = h1[bin];
    if (c) atomicAdd(&ghist[b*NB1 + bin], c);
  }
}

// ---------- D3: 16 blocks — B1 + count-above from the 2048-bin global hist ----------
__global__ __launch_bounds__(256) void ks1(const int* __restrict__ ghist, Accum* acc) {
  const int b = blockIdx.x;
  const int* hb = ghist + b*NB1;
  const int tid = threadIdx.x, lane = tid & 63, wave = tid >> 6;
  const int npos = acc->npos[b];
  const int k = npos > 0 ? 100*npos : 100;
  int hv[8];
  #pragma unroll
  for (int i = 0; i < 8; ++i) hv[i] = hb[tid*8 + i];
  int csum = 0;
  #pragma unroll
  for (int i = 0; i < 8; ++i) csum += hv[i];
  __shared__ int wt[4];
  int S = csum;
  #pragma unroll
  for (int off = 1; off < 64; off <<= 1) {
    const int t = __shfl_down(S, off, 64);
    if (lane + off < 64) S += t;
  }
  if (lane == 0) wt[wave] = S;
  __syncthreads();
  int above = 0;
  for (int w = wave + 1; w < 4; ++w) above += wt[w];
  const int sfx = above + (S - csum);
  if (sfx < k && sfx + csum >= k) {
    int run = sfx;
    for (int i = 7; i >= 0; --i) {
      if (run + hv[i] >= k) {
        acc->B1[b] = tid*8 + i;
        acc->cnt_above[b] = run;
        break;
      }
      run += hv[i];
    }
  }
}

// ---------- D4: fence-free gather (3456 blocks) ----------
__global__ __launch_bounds__(256) void kgather(const float* __restrict__ neg,
                                               float* __restrict__ list,
                                               float* __restrict__ psum,
                                               int* __restrict__ seg_cnt,
                                               const Accum* __restrict__ acc) {
  const int bid = blockIdx.x;
  const int tid = threadIdx.x, lane = tid & 63, wave = tid >> 6;
  const int b = bid / NSEG;
  const int seg = bid - b*NSEG;
  const int B1 = acc->B1[b];

  const int idx = b*AA + seg*256 + tid;
  const float val = neg[idx];
  const int bin = (int)(fkey(val) >> 21);
  const float aval = (bin > B1 && bin >= 1024) ? val : 0.0f;
  const float bs = blockReduceSumF(aval);

  const bool match = (bin == B1);
  const unsigned long long mask = __ballot(match);
  __shared__ int wc[4];
  if (lane == 0) wc[wave] = (int)__popcll(mask);
  __syncthreads();
  int wbase = 0;
  for (int w = 0; w < wave; ++w) wbase += wc[w];
  if (match) {
    const int pos = (int)__popcll(mask & ((1ull << lane) - 1ull));
    list[(size_t)b*AA + seg*256 + wbase + pos] = val;
  }
  if (tid == 0) {
    psum[bid] = bs;
    seg_cnt[bid] = wc[0] + wc[1] + wc[2] + wc[3];
  }
}

// ---------- D5: per-image selection (16 x 1024, stream-ordered) + fused final ----------
__global__ __launch_bounds__(1024) void ksel(const float* __restrict__ list,
                                             const float* __restrict__ psum,
                                             const int* __restrict__ seg_cnt,
                                             Accum* acc, float* __restrict__ out) {
  __shared__ int h[2048];
  __shared__ int cnS[NSEG];
  const int b = blockIdx.x;
  const int tid = threadIdx.x;
  const int npos = acc->npos[b];
  const int k = npos > 0 ? 100*npos : 100;
  const int B1 = acc->B1[b];
  const int cnt_above = acc->cnt_above[b];
  const float pos_sum = acc->pos_sum[b];

  const float pv = (tid < NSEG) ? psum[b*NSEG + tid] : 0.0f;
  const float sum_above = redF1024(pv);

  if (B1 < 1024) {   // k-th value negative: only nonneg values counted
    if (tid == 0) acc->per_img[b] = (pos_sum + sum_above) / fmaxf((float)npos, 1.0f);
  } else {
    if (tid < NSEG) cnS[tid] = seg_cnt[b*NSEG + tid];
    h[tid] = 0; h[tid + 1024] = 0;
    __syncthreads();
    const int kt2 = k - cnt_above;   // >= 1
    const float* lb = list + (size_t)b*AA;
    const int t = tid & 255;         // position within a segment
    const int so = tid >> 8;         // 4 segments processed in parallel
    __shared__ int sB2, sC2, sB3, sC3;

    // pass 1: level-2 hist (key bits 20..10); 4 segments wide, coalesced
    for (int s0 = 0; s0 < NSEG; s0 += 4) {
      const int s = s0 + so;
      if (s < NSEG && t < cnS[s]) {
        const float v = lb[s*256 + t];
        atomicAdd(&h[(fkey(v) >> 10) & 0x7FF], 1);
      }
    }
    __syncthreads();
    suffix_find_1024(h, 2048, kt2, &sB2, &sC2);
    const int B2 = sB2;
    const int kt3 = kt2 - sC2;       // >= 1
    h[tid] = 0;
    __syncthreads();

    // pass 2: msum/mcnt for sub > B2; level-3 hist for sub == B2
    float msum = 0.0f; int mcnt = 0;
    for (int s0 = 0; s0 < NSEG; s0 += 4) {
      const int s = s0 + so;
      if (s < NSEG && t < cnS[s]) {
        const float v = lb[s*256 + t];
        const unsigned key = fkey(v);
        const int sub = (int)((key >> 10) & 0x7FF);
        if (sub > B2) { msum += v; mcnt++; }
        else if (sub == B2) atomicAdd(&h[key & 0x3FF], 1);
      }
    }
    __syncthreads();
    suffix_find_1024(h, 1024, kt3, &sB3, &sC3);
    const int B3 = sB3;
    const unsigned Kstar = ((unsigned)B1 << 21) | ((unsigned)B2 << 10) | (unsigned)B3;
    const float vK = fkey_inv(Kstar);  // >= 0 since B1 >= 1024

    // pass 3: count/sum of sub == B2 with low bits > B3
    for (int s0 = 0; s0 < NSEG; s0 += 4) {
      const int s = s0 + so;
      if (s < NSEG && t < cnS[s]) {
        const float x = lb[s*256 + t];
        const unsigned key = fkey(x);
        if ((int)((key >> 10) & 0x7FF) == B2 && (int)(key & 0x3FF) > B3) { msum += x; mcnt++; }
      }
    }
    const int cg = redI1024(mcnt);
    const float sg = redF1024(msum);
    if (tid == 0) {
      const int total_gt = cnt_above + cg;
      const float ns = sum_above + sg + (float)(k - total_gt) * vK;
      acc->per_img[b] = (pos_sum + ns) / fmaxf((float)npos, 1.0f);
    }
  }

  // fused final: last of the 16 blocks writes out[0..3] (fences in 16 blocks only)
  __threadfence();
  __shared__ int lastAll;
  if (tid == 0) lastAll = (atomicAdd(&acc->done, 1) == BB - 1) ? 1 : 0;
  __syncthreads();
  if (!lastAll) return;
  __threadfence();
  if (tid == 0) {
    float s = 0.0f; int tot = 0;
    for (int b2 = 0; b2 < BB; ++b2) { s += acc->per_img[b2]; tot += acc->npos[b2]; }
    out[0] = s / (float)BB;
    const float denom = fmaxf((float)tot, 1.0f);
    out[1] = acc->shape_sum / (denom * 3.0f);
    out[2] = acc->off_sum / (denom * 3.0f);
    out[3] = 1.0f - acc->iou_sum / denom;
  }
}

extern "C" void kernel_launch(void* const* d_in, const int* in_sizes, int n_in,
                              void* d_out, int out_size, void* d_ws, size_t ws_size,
                              hipStream_t stream) {
  const float* cls_out    = (const float*)d_in[0];
  const float* shape_out  = (const float*)d_in[1];
  const float* offset_out = (const float*)d_in[2];
  const float* ann        = (const float*)d_in[3];
  float* out = (float*)d_out;

  char* ws = (char*)d_ws;
  Accum* acc    = (Accum*)ws;                               // < 1 KB
  int* plist    = (int*)(ws + 4096);                        // 128*7   = 3.6 KB
  int* ilist    = plist + (size_t)BB*NN*TOPKc;              // 128*182 = 93 KB
  int* ghist    = ilist + (size_t)BB*NN*NIGN;               // 32768   = 128 KB
  float* neg    = (float*)(ghist + (size_t)BB*NB1);         // 3.54 MB
  float* list   = neg + (size_t)BB*AA;                      // 3.54 MB
  float* psum   = list + (size_t)BB*AA;                     // 13.8 KB
  int* seg_cnt  = (int*)(psum + (size_t)BB*NSEG);           // 13.8 KB

  hipLaunchKernelGGL(k2_topk, dim3(BB*NN), dim3(256), 0, stream,
                     ann, plist, ilist, ghist, acc);
  hipLaunchKernelGGL(k3_loss, dim3(NBLK), dim3(256), 0, stream,
                     cls_out, shape_out, offset_out, ann, plist, ilist, neg, ghist, acc);
  hipLaunchKernelGGL(ks1, dim3(BB), dim3(256), 0, stream, ghist, acc);
  hipLaunchKernelGGL(kgather, dim3(NBLK), dim3(256), 0, stream,
                     neg, list, psum, seg_cnt, acc);
  hipLaunchKernelGGL(ksel, dim3(BB), dim3(1024), 0, stream,
                     list, psum, seg_cnt, acc, out);
}

// Round 14
// 96.728 us; speedup vs baseline: 4.9987x; 1.0915x over previous
//
#include <hip/hip_runtime.h>

#define BB 16
#define NN 8
#define DD 24
#define HH 48
#define WW 48
#define AA (DD*HH*WW)   // 55296
#define NSEG (AA/256)   // 216 segments per image
#define NBLK ((BB*AA)/256)  // 3456
#define TOPKc 7
#define KIGN 189        // (IGNORE_RATIO+1)*TOPK
#define NIGN 182        // exactly KIGN-TOPKc ignore marks per kept GT
#define NB1 2048        // level-1 bins = key >> 21

// fixed candidate window (shifted to stay in-grid): 13 x 25 x 25 = 8125
#define WZC 13
#define WYC 25
#define WXC 25
#define WYXC (WYC*WXC)          // 625
#define CNTC (WZC*WYXC)         // 8125
#define CPT 32                  // 32*256 = 8192 >= 8125

struct GT {
  float ctr[3];
  float half_[3];
  float bbox[6];
  float lo[3], hi[3];
  int keep, rejected;
};

struct Accum {
  int   npos[BB];
  float pos_sum[BB];
  float shape_sum, off_sum, iou_sum;
  float per_img[BB];
  int   B1[BB];
  int   cnt_above[BB];
  int   done;             // ksel image-tail done counter (16 blocks only)
};

__device__ __forceinline__ unsigned fkey(float f) {
  unsigned u = __float_as_uint(f);
  return (u & 0x80000000u) ? ~u : (u | 0x80000000u);
}
__device__ __forceinline__ float fkey_inv(unsigned k) {
  return __uint_as_float((k & 0x80000000u) ? (k & 0x7FFFFFFFu) : ~k);
}

// Wave-aggregated LDS histogram add (for heavily SKEWED bins, e.g. k3 level-1).
__device__ __forceinline__ void agg_lds_add(int* h, int bin) {
  const int lane = threadIdx.x & 63;
  unsigned long long todo = __ballot(bin >= 0);
  while (todo) {
    const int leader = __ffsll((unsigned long long)todo) - 1;
    const int lbin = __shfl(bin, leader, 64);
    const unsigned long long eq = __ballot(bin == lbin) & todo;
    if (lane == leader) atomicAdd(&h[lbin], (int)__popcll(eq));
    todo &= ~eq;
  }
}

__device__ __forceinline__ GT prep_gt(const float* __restrict__ p) {
  const float cz=p[0], cy=p[1], cx=p[2], sz=p[3], sy=p[4], sx=p[5], label=p[6];
  const bool has_box = label > -1.0f;
  const float loz = fmaxf(cz - sz*0.5f, 0.0f);
  const float loy = fmaxf(cy - sy*0.5f, 0.0f);
  const float lox = fmaxf(cx - sx*0.5f, 0.0f);
  const float hiz = fminf(cz + sz*0.5f, 96.0f);
  const float hiy = fminf(cy + sy*0.5f, 192.0f);
  const float hix = fminf(cx + sx*0.5f, 192.0f);
  const float nz = fmaxf(hiz - loz, 0.0f);
  const float ny = fmaxf(hiy - loy, 0.0f);
  const float nx = fmaxf(hix - lox, 0.0f);
  const float vol = nz * ny * nx;
  const float percent = vol / (sz * sy * sx);
  const bool good = (percent > 0.1f) && (vol >= 15.0f);
  const bool keep = has_box && (vol > 0.0f) && good;
  const bool rejected = has_box && (vol > 0.0f) && !good;
  GT g;
  const float ncz = loz + nz*0.5f, ncy = loy + ny*0.5f, ncx = lox + nx*0.5f;
  if (keep) {
    g.ctr[0]=ncz*0.25f; g.ctr[1]=ncy*0.25f; g.ctr[2]=ncx*0.25f;
    g.half_[0]=nz*0.5f; g.half_[1]=ny*0.5f; g.half_[2]=nx*0.5f;
    g.bbox[0]=ncz; g.bbox[1]=ncy; g.bbox[2]=ncx;
    g.bbox[3]=nz;  g.bbox[4]=ny;  g.bbox[5]=nx;
  } else {
    for (int j=0;j<3;++j){ g.ctr[j]=-0.25f; g.half_[j]=-0.5f; }
    for (int j=0;j<6;++j) g.bbox[j]=-1.0f;
  }
  g.lo[0]=loz; g.lo[1]=loy; g.lo[2]=lox;
  g.hi[0]=hiz; g.hi[1]=hiy; g.hi[2]=hix;
  g.keep = keep ? 1 : 0;
  g.rejected = rejected ? 1 : 0;
  return g;
}

__device__ __forceinline__ int blockReduceSumI(int v) {
  __shared__ int s[4];
  for (int off = 32; off; off >>= 1) v += __shfl_down(v, off, 64);
  if ((threadIdx.x & 63) == 0) s[threadIdx.x >> 6] = v;
  __syncthreads();
  int r = s[0] + s[1] + s[2] + s[3];
  __syncthreads();
  return r;
}
__device__ __forceinline__ float blockReduceSumF(float v) {
  __shared__ float s[4];
  for (int off = 32; off; off >>= 1) v += __shfl_down(v, off, 64);
  if ((threadIdx.x & 63) == 0) s[threadIdx.x >> 6] = v;
  __syncthreads();
  float r = s[0] + s[1] + s[2] + s[3];
  __syncthreads();
  return r;
}
__device__ __forceinline__ int redI1024(int v) {
  __shared__ int s[16];
  for (int off = 32; off; off >>= 1) v += __shfl_down(v, off, 64);
  if ((threadIdx.x & 63) == 0) s[threadIdx.x >> 6] = v;
  __syncthreads();
  int r = 0;
  #pragma unroll
  for (int w = 0; w < 16; ++w) r += s[w];
  __syncthreads();
  return r;
}
__device__ __forceinline__ float redF1024(float v) {
  __shared__ float s[16];
  for (int off = 32; off; off >>= 1) v += __shfl_down(v, off, 64);
  if ((threadIdx.x & 63) == 0) s[threadIdx.x >> 6] = v;
  __syncthreads();
  float r = 0.0f;
  #pragma unroll
  for (int w = 0; w < 16; ++w) r += s[w];
  __syncthreads();
  return r;
}

// 1024-thread suffix-find over nbins (1024 or 2048) LDS bins.
__device__ void suffix_find_1024(const int* h, int nbins, int ktarget,
                                 int* s_bin, int* s_cnt) {
  const int tid = threadIdx.x, lane = tid & 63, wave = tid >> 6;
  const int C = nbins >> 10;
  int csum = 0;
  for (int i = 0; i < C; ++i) csum += h[tid*C + i];
  __shared__ int wt[16];
  int S = csum;
  #pragma unroll
  for (int off = 1; off < 64; off <<= 1) {
    const int t = __shfl_down(S, off, 64);
    if (lane + off < 64) S += t;
  }
  if (lane == 0) wt[wave] = S;
  __syncthreads();
  int above = 0;
  for (int w = wave + 1; w < 16; ++w) above += wt[w];
  const int sfx = above + (S - csum);
  if (sfx < ktarget && sfx + csum >= ktarget) {
    int running = sfx;
    for (int i = C - 1; i >= 0; --i) {
      const int c = h[tid*C + i];
      if (running + c >= ktarget) { *s_bin = tid*C + i; *s_cnt = running; break; }
      running += c;
    }
  }
  __syncthreads();
}

// ---------- D1: per-GT top-7 / top-189 (128 blocks) + embedded init ----------
__global__ __launch_bounds__(256) void k2_topk(const float* __restrict__ ann,
                                               int* __restrict__ plist,
                                               int* __restrict__ ilist,
                                               int* __restrict__ ghist,
                                               Accum* acc) {
  const int bn = blockIdx.x;
  const int tid = threadIdx.x;
  // embedded init: ghist (128 blocks x 256 = BB*NB1 exactly), acc, list prefills
  ghist[bn*256 + tid] = 0;
  if (bn == 0) for (int i = tid; i < (int)(sizeof(Accum)/4); i += 256) ((int*)acc)[i] = 0;
  if (tid < TOPKc) plist[bn*TOPKc + tid] = -1;
  if (tid < NIGN) ilist[bn*NIGN + tid] = -1;

  const GT g = prep_gt(ann + bn*7);
  if (!g.keep) return;
  const float cz = g.ctr[0], cy = g.ctr[1], cx = g.ctr[2];
  const int rz = (int)floorf(cz + 0.5f);
  const int ry = (int)floorf(cy + 0.5f);
  const int rx = (int)floorf(cx + 0.5f);
  const int zlo = min(max(rz - 6, 0),  DD - WZC);
  const int ylo = min(max(ry - 12, 0), HH - WYC);
  const int xlo = min(max(rx - 12, 0), WW - WXC);

  __shared__ int h[1024];
  #pragma unroll
  for (int i = 0; i < 4; ++i) h[tid + i*256] = 0;
  __syncthreads();

#define K2_KEYAID(J, KEY, AID, VALID)                                   \
  const int ci = tid + (J)*256;                                         \
  const bool VALID = ci < CNTC;                                         \
  const int wz = ci / WYXC;                                             \
  const int rem = ci - wz*WYXC;                                         \
  const int wy = rem / WXC;                                             \
  const int wx = rem - wy*WXC;                                          \
  const int z = zlo + wz, y = ylo + wy, x = xlo + wx;                   \
  const float dz = (cz - (float)z) * 2.0f;                              \
  const float dy = cy - (float)y;                                       \
  const float dx = cx - (float)x;                                      \
  const unsigned KEY = fkey(-__builtin_fmaf(dz, dz, __builtin_fmaf(dy, dy, dx*dx))); \
  const int AID = (z*HH + y)*WW + x;

  // pass A: 1024-bin histogram of key>>21
  #pragma unroll
  for (int j = 0; j < CPT; ++j) {
    K2_KEYAID(j, key, aid, valid)
    (void)aid;
    if (valid) atomicAdd(&h[key >> 21], 1);
  }
  __syncthreads();

  // suffix scan: crossing bins for rank 7 and rank 189
  __shared__ int wt[4];
  __shared__ int sB7, sA7, sB9, sA9;
  const int lane = tid & 63, wave = tid >> 6;
  int csum = 0;
  #pragma unroll
  for (int i = 0; i < 4; ++i) csum += h[tid*4 + i];
  int Ssc = csum;
  #pragma unroll
  for (int off = 1; off < 64; off <<= 1) {
    const int t = __shfl_down(Ssc, off, 64);
    if (lane + off < 64) Ssc += t;
  }
  if (lane == 0) wt[wave] = Ssc;
  __syncthreads();
  int above = 0;
  for (int w = wave + 1; w < 4; ++w) above += wt[w];
  const int sfx = above + (Ssc - csum);
  if (sfx < TOPKc && sfx + csum >= TOPKc) {
    int run = sfx;
    for (int i = 3; i >= 0; --i) {
      const int c = h[tid*4 + i];
      if (run + c >= TOPKc) { sB7 = tid*4 + i; sA7 = run; break; }
      run += c;
    }
  }
  if (sfx < KIGN && sfx + csum >= KIGN) {
    int run = sfx;
    for (int i = 3; i >= 0; --i) {
      const int c = h[tid*4 + i];
      if (run + c >= KIGN) { sB9 = tid*4 + i; sA9 = run; break; }
      run += c;
    }
  }
  __syncthreads();
  const int B7 = sB7, A7 = sA7, B9 = sB9, A9 = sA9;

  // pass B: collect keys of crossing bins
  __shared__ unsigned kl7[512], kl9[512];
  __shared__ int n7s, n9s;
  if (tid == 0) { n7s = 0; n9s = 0; }
  __syncthreads();
  #pragma unroll
  for (int j = 0; j < CPT; ++j) {
    K2_KEYAID(j, key, aid, valid)
    (void)aid;
    if (valid) {
      const int bin = (int)(key >> 21);
      if (bin == B7) { const int p = atomicAdd(&n7s, 1); if (p < 512) kl7[p] = key; }
      if (bin == B9 && B9 != B7) { const int p = atomicAdd(&n9s, 1); if (p < 512) kl9[p] = key; }
    }
  }
  __syncthreads();

  // exact k-th key within crossing bin
  __shared__ unsigned sk7, sk9;
  __shared__ int scg7, scg9;
  const int T7c = min(n7s, 512), T9c = min(n9s, 512);
  for (int i = tid; i < T7c; i += 256) {
    const unsigned xv = kl7[i];
    int gt = 0, eq = 0;
    for (int j2 = 0; j2 < T7c; ++j2) { gt += (kl7[j2] > xv); eq += (kl7[j2] == xv); }
    if (A7 + gt < TOPKc && TOPKc <= A7 + gt + eq) { sk7 = xv; scg7 = A7 + gt; }
    if (B9 == B7 && A7 + gt < KIGN && KIGN <= A7 + gt + eq) { sk9 = xv; scg9 = A7 + gt; }
  }
  if (B9 != B7) {
    for (int i = tid; i < T9c; i += 256) {
      const unsigned xv = kl9[i];
      int gt = 0, eq = 0;
      for (int j2 = 0; j2 < T9c; ++j2) { gt += (kl9[j2] > xv); eq += (kl9[j2] == xv); }
      if (A9 + gt < KIGN && KIGN <= A9 + gt + eq) { sk9 = xv; scg9 = A9 + gt; }
    }
  }
  __syncthreads();
  const unsigned k7 = sk7, k9 = sk9;
  const int cg7 = scg7, cg9 = scg9;

  // pass C: boundary-tie anchor lists, index-ranked
  __shared__ int tc7, tc9;
  __shared__ int tl7[256], tr7[256], tl9[256], tr9[256];
  if (tid == 0) { tc7 = 0; tc9 = 0; }
  __syncthreads();
  #pragma unroll
  for (int j = 0; j < CPT; ++j) {
    K2_KEYAID(j, key, aid, valid)
    if (valid) {
      if (key == k7) { const int p = atomicAdd(&tc7, 1); if (p < 256) tl7[p] = aid; }
      if (key == k9 && k9 != k7) { const int p = atomicAdd(&tc9, 1); if (p < 256) tl9[p] = aid; }
    }
  }
  __syncthreads();
  const int T7 = min(tc7, 256), T9 = min(tc9, 256);
  for (int i = tid; i < T7; i += 256) {
    const int ai = tl7[i]; int r = 0;
    for (int j2 = 0; j2 < T7; ++j2) r += (tl7[j2] < ai);
    tr7[i] = r;
  }
  for (int i = tid; i < T9; i += 256) {
    const int ai = tl9[i]; int r = 0;
    for (int j2 = 0; j2 < T9; ++j2) r += (tl9[j2] < ai);
    tr9[i] = r;
  }
  __shared__ int pcnt, icnt;
  if (tid == 0) { pcnt = 0; icnt = 0; }
  __syncthreads();

  // pass D: mark (top -> plist append; ignore -> ilist append); exclusive slices
  #pragma unroll
  for (int j = 0; j < CPT; ++j) {
    K2_KEYAID(j, key, aid, valid)
    if (valid) {
      bool top = false, igf = false;
      if (key > k7) top = true;
      else if (key == k7) {
        int r = 0;
        for (int t = 0; t < T7; ++t) if (tl7[t] == aid) r = tr7[t];
        const int ov = cg7 + r;
        if (ov < TOPKc) top = true;
        else if (ov < KIGN) igf = true;
      } else if (key > k9) igf = true;
      else if (key == k9) {
        int r = 0;
        for (int t = 0; t < T9; ++t) if (tl9[t] == aid) r = tr9[t];
        if (cg9 + r < KIGN) igf = true;
      }
      if (top) { const int s = atomicAdd(&pcnt, 1); if (s < TOPKc) plist[bn*TOPKc + s] = aid; }
      else if (igf) { const int s = atomicAdd(&icnt, 1); if (s < NIGN) ilist[bn*NIGN + s] = aid; }
    }
  }
#undef K2_KEYAID
}

// ---------- D2: per-anchor losses + level-1 hist (ignore mask from ilist) ----------
__global__ __launch_bounds__(256) void k3_loss(
    const float* __restrict__ cls_out, const float* __restrict__ shape_out,
    const float* __restrict__ offset_out, const float* __restrict__ ann,
    const int* __restrict__ plist, const int* __restrict__ ilist,
    float* __restrict__ neg, int* __restrict__ ghist, Accum* acc) {
  __shared__ GT sg[NN];
  __shared__ int pl[NN*TOPKc];
  __shared__ int h1[NB1];
  __shared__ unsigned ibm[8];   // 256-bit ignore mask for this block's anchors
  const int idx = blockIdx.x * 256 + threadIdx.x;
  const int b = idx / AA;            // AA%256==0 -> block-uniform
  const int a = idx - b * AA;
  const int abase = (blockIdx.x % NSEG) * 256;
  if (threadIdx.x < NN) sg[threadIdx.x] = prep_gt(ann + (b*NN + threadIdx.x)*7);
  if (threadIdx.x < NN*TOPKc) pl[threadIdx.x] = plist[b*NN*TOPKc + threadIdx.x];
  if (threadIdx.x < 8) ibm[threadIdx.x] = 0u;
  #pragma unroll
  for (int i = 0; i < NB1/256; ++i) h1[threadIdx.x + i*256] = 0;
  __syncthreads();
  // rebuild ignore bits: 1456 ids, ~6 per thread, L2-hot
  for (int i = threadIdx.x; i < NN*NIGN; i += 256) {
    const int id = ilist[b*NN*NIGN + i];
    const int rel = id - abase;
    if (rel >= 0 && rel < 256) atomicOr(&ibm[rel >> 5], 1u << (rel & 31));
  }
  __syncthreads();

  const int z = a / (HH*WW);
  const int rr = a - z*(HH*WW);
  const int y = rr / WW;
  const int x = rr - y*WW;

  float gign = 0.0f;
  for (int n = 0; n < NN; ++n) {
    if (!sg[n].rejected) continue;
    if ((float)z >= floorf(sg[n].lo[0]) && (float)z < ceilf(sg[n].hi[0]) &&
        (float)y >= floorf(sg[n].lo[1]) && (float)y < ceilf(sg[n].hi[1]) &&
        (float)x >= floorf(sg[n].lo[2]) && (float)x < ceilf(sg[n].hi[2])) gign = -1.0f;
  }

  int pn = NN;
  #pragma unroll
  for (int j = NN*TOPKc - 1; j >= 0; --j) if (pl[j] == a) pn = j / TOPKc;
  const bool is_pos = (pn < NN);
  const float target = is_pos ? 1.0f : 0.0f;
  const int ibit = (ibm[threadIdx.x >> 5] >> (threadIdx.x & 31)) & 1;
  const float ignore = (ibit ? -1.0f : 0.0f) + gign;
  const float pred = cls_out[idx];
  float prob = 1.0f / (1.0f + expf(-pred));
  prob = fminf(fmaxf(prob, 1e-4f), 1.0f - 1e-4f);
  const float alpha_f = is_pos ? 0.75f : 0.25f;
  const float pt = is_pos ? (1.0f - prob) : prob;
  const float fw = alpha_f * pt * pt;
  const float bce = fmaxf(pred, 0.0f) + log1pf(expf(-fabsf(pred))) - pred * target;
  float loss = (ignore == 0.0f) ? fw * bce : 0.0f;
  if (prob < 0.8f && is_pos) loss *= 4.0f;
  const float nval = is_pos ? -1.0f : loss;
  neg[idx] = nval;

  agg_lds_add(h1, (int)(fkey(nval) >> 21));

  const int np = blockReduceSumI(is_pos ? 1 : 0);
  const float ps = blockReduceSumF(is_pos ? loss : 0.0f);
  if (threadIdx.x == 0 && np) {
    atomicAdd(&acc->npos[b], np);
    atomicAdd(&acc->pos_sum[b], ps);
  }

  if (is_pos) {
    const GT& g = sg[pn];
    const float toz = g.ctr[0] - (float)z;
    const float toy = g.ctr[1] - (float)y;
    const float tox = g.ctr[2] - (float)x;
    const float poz = offset_out[((size_t)b*3 + 0)*AA + a];
    const float poy = offset_out[((size_t)b*3 + 1)*AA + a];
    const float pox = offset_out[((size_t)b*3 + 2)*AA + a];
    const float psz = shape_out[((size_t)b*3 + 0)*AA + a];
    const float psy = shape_out[((size_t)b*3 + 1)*AA + a];
    const float psx = shape_out[((size_t)b*3 + 2)*AA + a];
    const float off_t = fabsf(poz - toz) + fabsf(poy - toy) + fabsf(pox - tox);
    const float shp_t = fabsf(psz - g.half_[0]) + fabsf(psy - g.half_[1]) + fabsf(psx - g.half_[2]);
    const float c1z = ((float)z + poz) * 4.0f;
    const float c1y = ((float)y + poy) * 4.0f;
    const float c1x = ((float)x + pox) * 4.0f;
    const float s1z = 2.0f*psz, s1y = 2.0f*psy, s1x = 2.0f*psx;
    const float lo1z = c1z - s1z*0.5f, hi1z = c1z + s1z*0.5f;
    const float lo1y = c1y - s1y*0.5f, hi1y = c1y + s1y*0.5f;
    const float lo1x = c1x - s1x*0.5f, hi1x = c1x + s1x*0.5f;
    const float c2z = g.bbox[0], c2y = g.bbox[1], c2x = g.bbox[2];
    const float s2z = g.bbox[3], s2y = g.bbox[4], s2x = g.bbox[5];
    const float lo2z = c2z - s2z*0.5f, hi2z = c2z + s2z*0.5f;
    const float lo2y = c2y - s2y*0.5f, hi2y = c2y + s2y*0.5f;
    const float lo2x = c2x - s2x*0.5f, hi2x = c2x + s2x*0.5f;
    const float iz = fmaxf(fminf(hi1z,hi2z) - fmaxf(lo1z,lo2z), 0.0f);
    const float iy = fmaxf(fminf(hi1y,hi2y) - fmaxf(lo1y,lo2y), 0.0f);
    const float ix = fmaxf(fminf(hi1x,hi2x) - fmaxf(lo1x,lo2x), 0.0f);
    const float inter = iz*iy*ix + 1e-7f;
    const float uni = s1z*s1y*s1x + s2z*s2y*s2x - inter;
    const float iou = inter / uni;
    const float ez = fmaxf(hi1z,hi2z) - fminf(lo1z,lo2z);
    const float ey = fmaxf(hi1y,hi2y) - fminf(lo1y,lo2y);
    const float ex = fmaxf(hi1x,hi2x) - fminf(lo1x,lo2x);
    const float c2d = (ez*ez + ey*ey) + ex*ex + 1e-7f;
    const float rz2 = (lo2z + hi2z) - (lo1z + hi1z);
    const float ry2 = (lo2y + hi2y) - (lo1y + hi1y);
    const float rx2 = (lo2x + hi2x) - (lo1x + hi1x);
    const float rho2 = ((rz2*rz2 + ry2*ry2) + rx2*rx2) * 0.25f;
    const float diou = iou - rho2 / c2d;
    atomicAdd(&acc->shape_sum, shp_t);
    atomicAdd(&acc->off_sum, off_t);
    atomicAdd(&acc->iou_sum, diou);
  }

  __syncthreads();
  #pragma unroll
  for (int i = 0; i < NB1/256; ++i) {
    const int bin = threadIdx.x + i*256;
    const int c = h1[bin];
    if (c) atomicAdd(&ghist[b*NB1 + bin], c);
  }
}

// ---------- D3: 16 blocks — B1 + count-above from the 2048-bin global hist ----------
__global__ __launch_bounds__(256) void ks1(const int* __restrict__ ghist, Accum* acc) {
  const int b = blockIdx.x;
  const int* hb = ghist + b*NB1;
  const int tid = threadIdx.x, lane = tid & 63, wave = tid >> 6;
  const int npos = acc->npos[b];
  const int k = npos > 0 ? 100*npos : 100;
  int hv[8];
  #pragma unroll
  for (int i = 0; i < 8; ++i) hv[i] = hb[tid*8 + i];
  int csum = 0;
  #pragma unroll
  for (int i = 0; i < 8; ++i) csum += hv[i];
  __shared__ int wt[4];
  int S = csum;
  #pragma unroll
  for (int off = 1; off < 64; off <<= 1) {
    const int t = __shfl_down(S, off, 64);
    if (lane + off < 64) S += t;
  }
  if (lane == 0) wt[wave] = S;
  __syncthreads();
  int above = 0;
  for (int w = wave + 1; w < 4; ++w) above += wt[w];
  const int sfx = above + (S - csum);
  if (sfx < k && sfx + csum >= k) {
    int run = sfx;
    for (int i = 7; i >= 0; --i) {
      if (run + hv[i] >= k) {
        acc->B1[b] = tid*8 + i;
        acc->cnt_above[b] = run;
        break;
      }
      run += hv[i];
    }
  }
}

// ---------- D4: fence-free gather (3456 blocks) ----------
__global__ __launch_bounds__(256) void kgather(const float* __restrict__ neg,
                                               float* __restrict__ list,
                                               float* __restrict__ psum,
                                               int* __restrict__ seg_cnt,
                                               const Accum* __restrict__ acc) {
  const int bid = blockIdx.x;
  const int tid = threadIdx.x, lane = tid & 63, wave = tid >> 6;
  const int b = bid / NSEG;
  const int seg = bid - b*NSEG;
  const int B1 = acc->B1[b];

  const int idx = b*AA + seg*256 + tid;
  const float val = neg[idx];
  const int bin = (int)(fkey(val) >> 21);
  const float aval = (bin > B1 && bin >= 1024) ? val : 0.0f;
  const float bs = blockReduceSumF(aval);

  const bool match = (bin == B1);
  const unsigned long long mask = __ballot(match);
  __shared__ int wc[4];
  if (lane == 0) wc[wave] = (int)__popcll(mask);
  __syncthreads();
  int wbase = 0;
  for (int w = 0; w < wave; ++w) wbase += wc[w];
  if (match) {
    const int pos = (int)__popcll(mask & ((1ull << lane) - 1ull));
    list[(size_t)b*AA + seg*256 + wbase + pos] = val;
  }
  if (tid == 0) {
    psum[bid] = bs;
    seg_cnt[bid] = wc[0] + wc[1] + wc[2] + wc[3];
  }
}

// ---------- D5: per-image selection (16 x 1024, batched pipelined loads) + fused final ----------
__global__ __launch_bounds__(1024) void ksel(const float* __restrict__ list,
                                             const float* __restrict__ psum,
                                             const int* __restrict__ seg_cnt,
                                             Accum* acc, float* __restrict__ out) {
  __shared__ int h[2048];
  __shared__ int cnS[NSEG];
  const int b = blockIdx.x;
  const int tid = threadIdx.x;
  const int npos = acc->npos[b];
  const int k = npos > 0 ? 100*npos : 100;
  const int B1 = acc->B1[b];
  const int cnt_above = acc->cnt_above[b];
  const float pos_sum = acc->pos_sum[b];

  const float pv = (tid < NSEG) ? psum[b*NSEG + tid] : 0.0f;
  const float sum_above = redF1024(pv);

  if (B1 < 1024) {   // k-th value negative: only nonneg values counted
    if (tid == 0) acc->per_img[b] = (pos_sum + sum_above) / fmaxf((float)npos, 1.0f);
  } else {
    if (tid < NSEG) cnS[tid] = seg_cnt[b*NSEG + tid];
    h[tid] = 0; h[tid + 1024] = 0;
    __syncthreads();
    const int kt2 = k - cnt_above;   // >= 1
    const float* lb = list + (size_t)b*AA;
    const int t = tid & 255;         // position within a segment
    const int so = tid >> 8;         // thread's segment-group: s = so + 4*j, j=0..53
    __shared__ int sB2, sC2, sB3, sC3;

    // pass 1: level-2 hist (key bits 20..10); batched UNCONDITIONAL loads
    // (list slots past cnS[s] hold garbage; gate at USE, never at load ->
    //  8 independent loads in flight, no per-iteration branch-serialized latency)
    for (int j0 = 0; j0 < 56; j0 += 8) {
      float v[8];
      #pragma unroll
      for (int i = 0; i < 8; ++i) {
        const int j = j0 + i;
        v[i] = (j < 54) ? lb[(so + 4*j)*256 + t] : 0.0f;
      }
      #pragma unroll
      for (int i = 0; i < 8; ++i) {
        const int j = j0 + i;
        if (j < 54 && t < cnS[so + 4*j])
          atomicAdd(&h[(fkey(v[i]) >> 10) & 0x7FF], 1);
      }
    }
    __syncthreads();
    suffix_find_1024(h, 2048, kt2, &sB2, &sC2);
    const int B2 = sB2;
    const int kt3 = kt2 - sC2;       // >= 1
    h[tid] = 0;
    __syncthreads();

    // pass 2: msum/mcnt for sub > B2; level-3 hist for sub == B2 (batched loads)
    float msum = 0.0f; int mcnt = 0;
    for (int j0 = 0; j0 < 56; j0 += 8) {
      float v[8];
      #pragma unroll
      for (int i = 0; i < 8; ++i) {
        const int j = j0 + i;
        v[i] = (j < 54) ? lb[(so + 4*j)*256 + t] : 0.0f;
      }
      #pragma unroll
      for (int i = 0; i < 8; ++i) {
        const int j = j0 + i;
        if (j < 54 && t < cnS[so + 4*j]) {
          const unsigned key = fkey(v[i]);
          const int sub = (int)((key >> 10) & 0x7FF);
          if (sub > B2) { msum += v[i]; mcnt++; }
          else if (sub == B2) atomicAdd(&h[key & 0x3FF], 1);
        }
      }
    }
    __syncthreads();
    suffix_find_1024(h, 1024, kt3, &sB3, &sC3);
    const int B3 = sB3;
    const unsigned Kstar = ((unsigned)B1 << 21) | ((unsigned)B2 << 10) | (unsigned)B3;
    const float vK = fkey_inv(Kstar);  // >= 0 since B1 >= 1024

    // pass 3: count/sum of sub == B2 with low bits > B3 (batched loads)
    for (int j0 = 0; j0 < 56; j0 += 8) {
      float v[8];
      #pragma unroll
      for (int i = 0; i < 8; ++i) {
        const int j = j0 + i;
        v[i] = (j < 54) ? lb[(so + 4*j)*256 + t] : 0.0f;
      }
      #pragma unroll
      for (int i = 0; i < 8; ++i) {
        const int j = j0 + i;
        if (j < 54 && t < cnS[so + 4*j]) {
          const unsigned key = fkey(v[i]);
          if ((int)((key >> 10) & 0x7FF) == B2 && (int)(key & 0x3FF) > B3) { msum += v[i]; mcnt++; }
        }
      }
    }
    const int cg = redI1024(mcnt);
    const float sg = redF1024(msum);
    if (tid == 0) {
      const int total_gt = cnt_above + cg;
      const float ns = sum_above + sg + (float)(k - total_gt) * vK;
      acc->per_img[b] = (pos_sum + ns) / fmaxf((float)npos, 1.0f);
    }
  }

  // fused final: last of the 16 blocks writes out[0..3] (fences in 16 blocks only)
  __threadfence();
  __shared__ int lastAll;
  if (tid == 0) lastAll = (atomicAdd(&acc->done, 1) == BB - 1) ? 1 : 0;
  __syncthreads();
  if (!lastAll) return;
  __threadfence();
  if (tid == 0) {
    float s = 0.0f; int tot = 0;
    for (int b2 = 0; b2 < BB; ++b2) { s += acc->per_img[b2]; tot += acc->npos[b2]; }
    out[0] = s / (float)BB;
    const float denom = fmaxf((float)tot, 1.0f);
    out[1] = acc->shape_sum / (denom * 3.0f);
    out[2] = acc->off_sum / (denom * 3.0f);
    out[3] = 1.0f - acc->iou_sum / denom;
  }
}

extern "C" void kernel_launch(void* const* d_in, const int* in_sizes, int n_in,
                              void* d_out, int out_size, void* d_ws, size_t ws_size,
                              hipStream_t stream) {
  const float* cls_out    = (const float*)d_in[0];
  const float* shape_out  = (const float*)d_in[1];
  const float* offset_out = (const float*)d_in[2];
  const float* ann        = (const float*)d_in[3];
  float* out = (float*)d_out;

  char* ws = (char*)d_ws;
  Accum* acc    = (Accum*)ws;                               // < 1 KB
  int* plist    = (int*)(ws + 4096);                        // 128*7   = 3.6 KB
  int* ilist    = plist + (size_t)BB*NN*TOPKc;              // 128*182 = 93 KB
  int* ghist    = ilist + (size_t)BB*NN*NIGN;               // 32768   = 128 KB
  float* neg    = (float*)(ghist + (size_t)BB*NB1);         // 3.54 MB
  float* list   = neg + (size_t)BB*AA;                      // 3.54 MB
  float* psum   = list + (size_t)BB*AA;                     // 13.8 KB
  int* seg_cnt  = (int*)(psum + (size_t)BB*NSEG);           // 13.8 KB

  hipLaunchKernelGGL(k2_topk, dim3(BB*NN), dim3(256), 0, stream,
                     ann, plist, ilist, ghist, acc);
  hipLaunchKernelGGL(k3_loss, dim3(NBLK), dim3(256), 0, stream,
                     cls_out, shape_out, offset_out, ann, plist, ilist, neg, ghist, acc);
  hipLaunchKernelGGL(ks1, dim3(BB), dim3(256), 0, stream, ghist, acc);
  hipLaunchKernelGGL(kgather, dim3(NBLK), dim3(256), 0, stream,
                     neg, list, psum, seg_cnt, acc);
  hipLaunchKernelGGL(ksel, dim3(BB), dim3(1024), 0, stream,
                     list, psum, seg_cnt, acc, out);
}

// Round 15
// 92.897 us; speedup vs baseline: 5.2048x; 1.0412x over previous
//
#include <hip/hip_runtime.h>

#define BB 16
#define NN 8
#define DD 24
#define HH 48
#define WW 48
#define AA (DD*HH*WW)   // 55296
#define NSEG (AA/256)   // 216 segments per image
#define NBLK ((BB*AA)/256)  // 3456
#define TOPKc 7
#define KIGN 189        // (IGNORE_RATIO+1)*TOPK
#define NIGN 182        // exactly KIGN-TOPKc ignore marks per kept GT
#define NB1 2048        // level-1 bins = key >> 21
#define DCAP 16384      // dense survivor LDS cache in ksel (64 KB)

// fixed candidate window (shifted to stay in-grid): 13 x 25 x 25 = 8125
#define WZC 13
#define WYC 25
#define WXC 25
#define WYXC (WYC*WXC)          // 625
#define CNTC (WZC*WYXC)         // 8125
#define CPT 32                  // 32*256 = 8192 >= 8125

struct GT {
  float ctr[3];
  float half_[3];
  float bbox[6];
  float lo[3], hi[3];
  int keep, rejected;
};

struct Accum {
  int   npos[BB];
  float pos_sum[BB];
  float shape_sum, off_sum, iou_sum;
  float per_img[BB];
  int   B1[BB];
  int   cnt_above[BB];
  int   done;             // ksel image-tail done counter (16 blocks only)
  int   cursor[BB*32];    // padded per-image dense-append cursors (use b*32)
};

__device__ __forceinline__ unsigned fkey(float f) {
  unsigned u = __float_as_uint(f);
  return (u & 0x80000000u) ? ~u : (u | 0x80000000u);
}
__device__ __forceinline__ float fkey_inv(unsigned k) {
  return __uint_as_float((k & 0x80000000u) ? (k & 0x7FFFFFFFu) : ~k);
}

// Wave-aggregated LDS histogram add (for heavily SKEWED bins).
__device__ __forceinline__ void agg_lds_add(int* h, int bin) {
  const int lane = threadIdx.x & 63;
  unsigned long long todo = __ballot(bin >= 0);
  while (todo) {
    const int leader = __ffsll((unsigned long long)todo) - 1;
    const int lbin = __shfl(bin, leader, 64);
    const unsigned long long eq = __ballot(bin == lbin) & todo;
    if (lane == leader) atomicAdd(&h[lbin], (int)__popcll(eq));
    todo &= ~eq;
  }
}

__device__ __forceinline__ GT prep_gt(const float* __restrict__ p) {
  const float cz=p[0], cy=p[1], cx=p[2], sz=p[3], sy=p[4], sx=p[5], label=p[6];
  const bool has_box = label > -1.0f;
  const float loz = fmaxf(cz - sz*0.5f, 0.0f);
  const float loy = fmaxf(cy - sy*0.5f, 0.0f);
  const float lox = fmaxf(cx - sx*0.5f, 0.0f);
  const float hiz = fminf(cz + sz*0.5f, 96.0f);
  const float hiy = fminf(cy + sy*0.5f, 192.0f);
  const float hix = fminf(cx + sx*0.5f, 192.0f);
  const float nz = fmaxf(hiz - loz, 0.0f);
  const float ny = fmaxf(hiy - loy, 0.0f);
  const float nx = fmaxf(hix - lox, 0.0f);
  const float vol = nz * ny * nx;
  const float percent = vol / (sz * sy * sx);
  const bool good = (percent > 0.1f) && (vol >= 15.0f);
  const bool keep = has_box && (vol > 0.0f) && good;
  const bool rejected = has_box && (vol > 0.0f) && !good;
  GT g;
  const float ncz = loz + nz*0.5f, ncy = loy + ny*0.5f, ncx = lox + nx*0.5f;
  if (keep) {
    g.ctr[0]=ncz*0.25f; g.ctr[1]=ncy*0.25f; g.ctr[2]=ncx*0.25f;
    g.half_[0]=nz*0.5f; g.half_[1]=ny*0.5f; g.half_[2]=nx*0.5f;
    g.bbox[0]=ncz; g.bbox[1]=ncy; g.bbox[2]=ncx;
    g.bbox[3]=nz;  g.bbox[4]=ny;  g.bbox[5]=nx;
  } else {
    for (int j=0;j<3;++j){ g.ctr[j]=-0.25f; g.half_[j]=-0.5f; }
    for (int j=0;j<6;++j) g.bbox[j]=-1.0f;
  }
  g.lo[0]=loz; g.lo[1]=loy; g.lo[2]=lox;
  g.hi[0]=hiz; g.hi[1]=hiy; g.hi[2]=hix;
  g.keep = keep ? 1 : 0;
  g.rejected = rejected ? 1 : 0;
  return g;
}

__device__ __forceinline__ int blockReduceSumI(int v) {
  __shared__ int s[4];
  for (int off = 32; off; off >>= 1) v += __shfl_down(v, off, 64);
  if ((threadIdx.x & 63) == 0) s[threadIdx.x >> 6] = v;
  __syncthreads();
  int r = s[0] + s[1] + s[2] + s[3];
  __syncthreads();
  return r;
}
__device__ __forceinline__ float blockReduceSumF(float v) {
  __shared__ float s[4];
  for (int off = 32; off; off >>= 1) v += __shfl_down(v, off, 64);
  if ((threadIdx.x & 63) == 0) s[threadIdx.x >> 6] = v;
  __syncthreads();
  float r = s[0] + s[1] + s[2] + s[3];
  __syncthreads();
  return r;
}
__device__ __forceinline__ int redI1024(int v) {
  __shared__ int s[16];
  for (int off = 32; off; off >>= 1) v += __shfl_down(v, off, 64);
  if ((threadIdx.x & 63) == 0) s[threadIdx.x >> 6] = v;
  __syncthreads();
  int r = 0;
  #pragma unroll
  for (int w = 0; w < 16; ++w) r += s[w];
  __syncthreads();
  return r;
}
__device__ __forceinline__ float redF1024(float v) {
  __shared__ float s[16];
  for (int off = 32; off; off >>= 1) v += __shfl_down(v, off, 64);
  if ((threadIdx.x & 63) == 0) s[threadIdx.x >> 6] = v;
  __syncthreads();
  float r = 0.0f;
  #pragma unroll
  for (int w = 0; w < 16; ++w) r += s[w];
  __syncthreads();
  return r;
}

// 1024-thread suffix-find over nbins (1024 or 2048) LDS bins.
__device__ void suffix_find_1024(const int* h, int nbins, int ktarget,
                                 int* s_bin, int* s_cnt) {
  const int tid = threadIdx.x, lane = tid & 63, wave = tid >> 6;
  const int C = nbins >> 10;
  int csum = 0;
  for (int i = 0; i < C; ++i) csum += h[tid*C + i];
  __shared__ int wt[16];
  int S = csum;
  #pragma unroll
  for (int off = 1; off < 64; off <<= 1) {
    const int t = __shfl_down(S, off, 64);
    if (lane + off < 64) S += t;
  }
  if (lane == 0) wt[wave] = S;
  __syncthreads();
  int above = 0;
  for (int w = wave + 1; w < 16; ++w) above += wt[w];
  const int sfx = above + (S - csum);
  if (sfx < ktarget && sfx + csum >= ktarget) {
    int running = sfx;
    for (int i = C - 1; i >= 0; --i) {
      const int c = h[tid*C + i];
      if (running + c >= ktarget) { *s_bin = tid*C + i; *s_cnt = running; break; }
      running += c;
    }
  }
  __syncthreads();
}

// ---------- D1: per-GT top-7 / top-189 (128 blocks) + embedded init ----------
__global__ __launch_bounds__(256) void k2_topk(const float* __restrict__ ann,
                                               int* __restrict__ plist,
                                               int* __restrict__ ilist,
                                               int* __restrict__ ghist,
                                               Accum* acc) {
  const int bn = blockIdx.x;
  const int tid = threadIdx.x;
  // embedded init: ghist (128 blocks x 256 = BB*NB1 exactly), acc, list prefills
  ghist[bn*256 + tid] = 0;
  if (bn == 0) for (int i = tid; i < (int)(sizeof(Accum)/4); i += 256) ((int*)acc)[i] = 0;
  if (tid < TOPKc) plist[bn*TOPKc + tid] = -1;
  if (tid < NIGN) ilist[bn*NIGN + tid] = -1;

  const GT g = prep_gt(ann + bn*7);
  if (!g.keep) return;
  const float cz = g.ctr[0], cy = g.ctr[1], cx = g.ctr[2];
  const int rz = (int)floorf(cz + 0.5f);
  const int ry = (int)floorf(cy + 0.5f);
  const int rx = (int)floorf(cx + 0.5f);
  const int zlo = min(max(rz - 6, 0),  DD - WZC);
  const int ylo = min(max(ry - 12, 0), HH - WYC);
  const int xlo = min(max(rx - 12, 0), WW - WXC);

  __shared__ int h[1024];
  #pragma unroll
  for (int i = 0; i < 4; ++i) h[tid + i*256] = 0;
  __syncthreads();

#define K2_KEYAID(J, KEY, AID, VALID)                                   \
  const int ci = tid + (J)*256;                                         \
  const bool VALID = ci < CNTC;                                         \
  const int wz = ci / WYXC;                                             \
  const int rem = ci - wz*WYXC;                                         \
  const int wy = rem / WXC;                                             \
  const int wx = rem - wy*WXC;                                          \
  const int z = zlo + wz, y = ylo + wy, x = xlo + wx;                   \
  const float dz = (cz - (float)z) * 2.0f;                              \
  const float dy = cy - (float)y;                                       \
  const float dx = cx - (float)x;                                      \
  const unsigned KEY = fkey(-__builtin_fmaf(dz, dz, __builtin_fmaf(dy, dy, dx*dx))); \
  const int AID = (z*HH + y)*WW + x;

  // pass A: 1024-bin histogram of key>>21
  #pragma unroll
  for (int j = 0; j < CPT; ++j) {
    K2_KEYAID(j, key, aid, valid)
    (void)aid;
    if (valid) atomicAdd(&h[key >> 21], 1);
  }
  __syncthreads();

  // suffix scan: crossing bins for rank 7 and rank 189
  __shared__ int wt[4];
  __shared__ int sB7, sA7, sB9, sA9;
  const int lane = tid & 63, wave = tid >> 6;
  int csum = 0;
  #pragma unroll
  for (int i = 0; i < 4; ++i) csum += h[tid*4 + i];
  int Ssc = csum;
  #pragma unroll
  for (int off = 1; off < 64; off <<= 1) {
    const int t = __shfl_down(Ssc, off, 64);
    if (lane + off < 64) Ssc += t;
  }
  if (lane == 0) wt[wave] = Ssc;
  __syncthreads();
  int above = 0;
  for (int w = wave + 1; w < 4; ++w) above += wt[w];
  const int sfx = above + (Ssc - csum);
  if (sfx < TOPKc && sfx + csum >= TOPKc) {
    int run = sfx;
    for (int i = 3; i >= 0; --i) {
      const int c = h[tid*4 + i];
      if (run + c >= TOPKc) { sB7 = tid*4 + i; sA7 = run; break; }
      run += c;
    }
  }
  if (sfx < KIGN && sfx + csum >= KIGN) {
    int run = sfx;
    for (int i = 3; i >= 0; --i) {
      const int c = h[tid*4 + i];
      if (run + c >= KIGN) { sB9 = tid*4 + i; sA9 = run; break; }
      run += c;
    }
  }
  __syncthreads();
  const int B7 = sB7, A7 = sA7, B9 = sB9, A9 = sA9;

  // pass B: collect keys of crossing bins
  __shared__ unsigned kl7[512], kl9[512];
  __shared__ int n7s, n9s;
  if (tid == 0) { n7s = 0; n9s = 0; }
  __syncthreads();
  #pragma unroll
  for (int j = 0; j < CPT; ++j) {
    K2_KEYAID(j, key, aid, valid)
    (void)aid;
    if (valid) {
      const int bin = (int)(key >> 21);
      if (bin == B7) { const int p = atomicAdd(&n7s, 1); if (p < 512) kl7[p] = key; }
      if (bin == B9 && B9 != B7) { const int p = atomicAdd(&n9s, 1); if (p < 512) kl9[p] = key; }
    }
  }
  __syncthreads();

  // exact k-th key within crossing bin
  __shared__ unsigned sk7, sk9;
  __shared__ int scg7, scg9;
  const int T7c = min(n7s, 512), T9c = min(n9s, 512);
  for (int i = tid; i < T7c; i += 256) {
    const unsigned xv = kl7[i];
    int gt = 0, eq = 0;
    for (int j2 = 0; j2 < T7c; ++j2) { gt += (kl7[j2] > xv); eq += (kl7[j2] == xv); }
    if (A7 + gt < TOPKc && TOPKc <= A7 + gt + eq) { sk7 = xv; scg7 = A7 + gt; }
    if (B9 == B7 && A7 + gt < KIGN && KIGN <= A7 + gt + eq) { sk9 = xv; scg9 = A7 + gt; }
  }
  if (B9 != B7) {
    for (int i = tid; i < T9c; i += 256) {
      const unsigned xv = kl9[i];
      int gt = 0, eq = 0;
      for (int j2 = 0; j2 < T9c; ++j2) { gt += (kl9[j2] > xv); eq += (kl9[j2] == xv); }
      if (A9 + gt < KIGN && KIGN <= A9 + gt + eq) { sk9 = xv; scg9 = A9 + gt; }
    }
  }
  __syncthreads();
  const unsigned k7 = sk7, k9 = sk9;
  const int cg7 = scg7, cg9 = scg9;

  // pass C: boundary-tie anchor lists, index-ranked
  __shared__ int tc7, tc9;
  __shared__ int tl7[256], tr7[256], tl9[256], tr9[256];
  if (tid == 0) { tc7 = 0; tc9 = 0; }
  __syncthreads();
  #pragma unroll
  for (int j = 0; j < CPT; ++j) {
    K2_KEYAID(j, key, aid, valid)
    if (valid) {
      if (key == k7) { const int p = atomicAdd(&tc7, 1); if (p < 256) tl7[p] = aid; }
      if (key == k9 && k9 != k7) { const int p = atomicAdd(&tc9, 1); if (p < 256) tl9[p] = aid; }
    }
  }
  __syncthreads();
  const int T7 = min(tc7, 256), T9 = min(tc9, 256);
  for (int i = tid; i < T7; i += 256) {
    const int ai = tl7[i]; int r = 0;
    for (int j2 = 0; j2 < T7; ++j2) r += (tl7[j2] < ai);
    tr7[i] = r;
  }
  for (int i = tid; i < T9; i += 256) {
    const int ai = tl9[i]; int r = 0;
    for (int j2 = 0; j2 < T9; ++j2) r += (tl9[j2] < ai);
    tr9[i] = r;
  }
  __shared__ int pcnt, icnt;
  if (tid == 0) { pcnt = 0; icnt = 0; }
  __syncthreads();

  // pass D: mark (top -> plist append; ignore -> ilist append); exclusive slices
  #pragma unroll
  for (int j = 0; j < CPT; ++j) {
    K2_KEYAID(j, key, aid, valid)
    if (valid) {
      bool top = false, igf = false;
      if (key > k7) top = true;
      else if (key == k7) {
        int r = 0;
        for (int t = 0; t < T7; ++t) if (tl7[t] == aid) r = tr7[t];
        const int ov = cg7 + r;
        if (ov < TOPKc) top = true;
        else if (ov < KIGN) igf = true;
      } else if (key > k9) igf = true;
      else if (key == k9) {
        int r = 0;
        for (int t = 0; t < T9; ++t) if (tl9[t] == aid) r = tr9[t];
        if (cg9 + r < KIGN) igf = true;
      }
      if (top) { const int s = atomicAdd(&pcnt, 1); if (s < TOPKc) plist[bn*TOPKc + s] = aid; }
      else if (igf) { const int s = atomicAdd(&icnt, 1); if (s < NIGN) ilist[bn*NIGN + s] = aid; }
    }
  }
#undef K2_KEYAID
}

// ---------- D2: per-anchor losses + level-1 hist (ignore mask from ilist) ----------
__global__ __launch_bounds__(256) void k3_loss(
    const float* __restrict__ cls_out, const float* __restrict__ shape_out,
    const float* __restrict__ offset_out, const float* __restrict__ ann,
    const int* __restrict__ plist, const int* __restrict__ ilist,
    float* __restrict__ neg, int* __restrict__ ghist, Accum* acc) {
  __shared__ GT sg[NN];
  __shared__ int pl[NN*TOPKc];
  __shared__ int h1[NB1];
  __shared__ unsigned ibm[8];   // 256-bit ignore mask for this block's anchors
  const int idx = blockIdx.x * 256 + threadIdx.x;
  const int b = idx / AA;            // AA%256==0 -> block-uniform
  const int a = idx - b * AA;
  const int abase = (blockIdx.x % NSEG) * 256;
  if (threadIdx.x < NN) sg[threadIdx.x] = prep_gt(ann + (b*NN + threadIdx.x)*7);
  if (threadIdx.x < NN*TOPKc) pl[threadIdx.x] = plist[b*NN*TOPKc + threadIdx.x];
  if (threadIdx.x < 8) ibm[threadIdx.x] = 0u;
  #pragma unroll
  for (int i = 0; i < NB1/256; ++i) h1[threadIdx.x + i*256] = 0;
  __syncthreads();
  // rebuild ignore bits: 1456 ids, ~6 per thread, L2-hot
  for (int i = threadIdx.x; i < NN*NIGN; i += 256) {
    const int id = ilist[b*NN*NIGN + i];
    const int rel = id - abase;
    if (rel >= 0 && rel < 256) atomicOr(&ibm[rel >> 5], 1u << (rel & 31));
  }
  __syncthreads();

  const int z = a / (HH*WW);
  const int rr = a - z*(HH*WW);
  const int y = rr / WW;
  const int x = rr - y*WW;

  float gign = 0.0f;
  for (int n = 0; n < NN; ++n) {
    if (!sg[n].rejected) continue;
    if ((float)z >= floorf(sg[n].lo[0]) && (float)z < ceilf(sg[n].hi[0]) &&
        (float)y >= floorf(sg[n].lo[1]) && (float)y < ceilf(sg[n].hi[1]) &&
        (float)x >= floorf(sg[n].lo[2]) && (float)x < ceilf(sg[n].hi[2])) gign = -1.0f;
  }

  int pn = NN;
  #pragma unroll
  for (int j = NN*TOPKc - 1; j >= 0; --j) if (pl[j] == a) pn = j / TOPKc;
  const bool is_pos = (pn < NN);
  const float target = is_pos ? 1.0f : 0.0f;
  const int ibit = (ibm[threadIdx.x >> 5] >> (threadIdx.x & 31)) & 1;
  const float ignore = (ibit ? -1.0f : 0.0f) + gign;
  const float pred = cls_out[idx];
  float prob = 1.0f / (1.0f + expf(-pred));
  prob = fminf(fmaxf(prob, 1e-4f), 1.0f - 1e-4f);
  const float alpha_f = is_pos ? 0.75f : 0.25f;
  const float pt = is_pos ? (1.0f - prob) : prob;
  const float fw = alpha_f * pt * pt;
  const float bce = fmaxf(pred, 0.0f) + log1pf(expf(-fabsf(pred))) - pred * target;
  float loss = (ignore == 0.0f) ? fw * bce : 0.0f;
  if (prob < 0.8f && is_pos) loss *= 4.0f;
  const float nval = is_pos ? -1.0f : loss;
  neg[idx] = nval;

  agg_lds_add(h1, (int)(fkey(nval) >> 21));

  const int np = blockReduceSumI(is_pos ? 1 : 0);
  const float ps = blockReduceSumF(is_pos ? loss : 0.0f);
  if (threadIdx.x == 0 && np) {
    atomicAdd(&acc->npos[b], np);
    atomicAdd(&acc->pos_sum[b], ps);
  }

  if (is_pos) {
    const GT& g = sg[pn];
    const float toz = g.ctr[0] - (float)z;
    const float toy = g.ctr[1] - (float)y;
    const float tox = g.ctr[2] - (float)x;
    const float poz = offset_out[((size_t)b*3 + 0)*AA + a];
    const float poy = offset_out[((size_t)b*3 + 1)*AA + a];
    const float pox = offset_out[((size_t)b*3 + 2)*AA + a];
    const float psz = shape_out[((size_t)b*3 + 0)*AA + a];
    const float psy = shape_out[((size_t)b*3 + 1)*AA + a];
    const float psx = shape_out[((size_t)b*3 + 2)*AA + a];
    const float off_t = fabsf(poz - toz) + fabsf(poy - toy) + fabsf(pox - tox);
    const float shp_t = fabsf(psz - g.half_[0]) + fabsf(psy - g.half_[1]) + fabsf(psx - g.half_[2]);
    const float c1z = ((float)z + poz) * 4.0f;
    const float c1y = ((float)y + poy) * 4.0f;
    const float c1x = ((float)x + pox) * 4.0f;
    const float s1z = 2.0f*psz, s1y = 2.0f*psy, s1x = 2.0f*psx;
    const float lo1z = c1z - s1z*0.5f, hi1z = c1z + s1z*0.5f;
    const float lo1y = c1y - s1y*0.5f, hi1y = c1y + s1y*0.5f;
    const float lo1x = c1x - s1x*0.5f, hi1x = c1x + s1x*0.5f;
    const float c2z = g.bbox[0], c2y = g.bbox[1], c2x = g.bbox[2];
    const float s2z = g.bbox[3], s2y = g.bbox[4], s2x = g.bbox[5];
    const float lo2z = c2z - s2z*0.5f, hi2z = c2z + s2z*0.5f;
    const float lo2y = c2y - s2y*0.5f, hi2y = c2y + s2y*0.5f;
    const float lo2x = c2x - s2x*0.5f, hi2x = c2x + s2x*0.5f;
    const float iz = fmaxf(fminf(hi1z,hi2z) - fmaxf(lo1z,lo2z), 0.0f);
    const float iy = fmaxf(fminf(hi1y,hi2y) - fmaxf(lo1y,lo2y), 0.0f);
    const float ix = fmaxf(fminf(hi1x,hi2x) - fmaxf(lo1x,lo2x), 0.0f);
    const float inter = iz*iy*ix + 1e-7f;
    const float uni = s1z*s1y*s1x + s2z*s2y*s2x - inter;
    const float iou = inter / uni;
    const float ez = fmaxf(hi1z,hi2z) - fminf(lo1z,lo2z);
    const float ey = fmaxf(hi1y,hi2y) - fminf(lo1y,lo2y);
    const float ex = fmaxf(hi1x,hi2x) - fminf(lo1x,lo2x);
    const float c2d = (ez*ez + ey*ey) + ex*ex + 1e-7f;
    const float rz2 = (lo2z + hi2z) - (lo1z + hi1z);
    const float ry2 = (lo2y + hi2y) - (lo1y + hi1y);
    const float rx2 = (lo2x + hi2x) - (lo1x + hi1x);
    const float rho2 = ((rz2*rz2 + ry2*ry2) + rx2*rx2) * 0.25f;
    const float diou = iou - rho2 / c2d;
    atomicAdd(&acc->shape_sum, shp_t);
    atomicAdd(&acc->off_sum, off_t);
    atomicAdd(&acc->iou_sum, diou);
  }

  __syncthreads();
  #pragma unroll
  for (int i = 0; i < NB1/256; ++i) {
    const int bin = threadIdx.x + i*256;
    const int c = h1[bin];
    if (c) atomicAdd(&ghist[b*NB1 + bin], c);
  }
}

// ---------- D3: 16 blocks — B1 + count-above from the 2048-bin global hist ----------
__global__ __launch_bounds__(256) void ks1(const int* __restrict__ ghist, Accum* acc) {
  const int b = blockIdx.x;
  const int* hb = ghist + b*NB1;
  const int tid = threadIdx.x, lane = tid & 63, wave = tid >> 6;
  const int npos = acc->npos[b];
  const int k = npos > 0 ? 100*npos : 100;
  int hv[8];
  #pragma unroll
  for (int i = 0; i < 8; ++i) hv[i] = hb[tid*8 + i];
  int csum = 0;
  #pragma unroll
  for (int i = 0; i < 8; ++i) csum += hv[i];
  __shared__ int wt[4];
  int S = csum;
  #pragma unroll
  for (int off = 1; off < 64; off <<= 1) {
    const int t = __shfl_down(S, off, 64);
    if (lane + off < 64) S += t;
  }
  if (lane == 0) wt[wave] = S;
  __syncthreads();
  int above = 0;
  for (int w = wave + 1; w < 4; ++w) above += wt[w];
  const int sfx = above + (S - csum);
  if (sfx < k && sfx + csum >= k) {
    int run = sfx;
    for (int i = 7; i >= 0; --i) {
      if (run + hv[i] >= k) {
        acc->B1[b] = tid*8 + i;
        acc->cnt_above[b] = run;
        break;
      }
      run += hv[i];
    }
  }
}

// ---------- D4: gather with DENSE per-image append (block-aggregated cursor) ----------
__global__ __launch_bounds__(256) void kgather(const float* __restrict__ neg,
                                               float* __restrict__ dense,
                                               float* __restrict__ psum,
                                               Accum* acc) {
  __shared__ float sv[256];
  __shared__ int sbase;
  const int bid = blockIdx.x;
  const int tid = threadIdx.x, lane = tid & 63, wave = tid >> 6;
  const int b = bid / NSEG;
  const int seg = bid - b*NSEG;
  const int B1 = acc->B1[b];

  const int idx = b*AA + seg*256 + tid;
  const float val = neg[idx];
  const int bin = (int)(fkey(val) >> 21);
  const float aval = (bin > B1 && bin >= 1024) ? val : 0.0f;
  const float bs = blockReduceSumF(aval);
  if (tid == 0) psum[bid] = bs;

  // compact survivors into LDS (deterministic within block)
  const bool match = (bin == B1);
  const unsigned long long mask = __ballot(match);
  __shared__ int wc[4];
  if (lane == 0) wc[wave] = (int)__popcll(mask);
  __syncthreads();
  int wbase = 0;
  for (int w = 0; w < wave; ++w) wbase += wc[w];
  if (match) {
    const int pos = (int)__popcll(mask & ((1ull << lane) - 1ull));
    sv[wbase + pos] = val;
  }
  const int blkc = wc[0] + wc[1] + wc[2] + wc[3];
  if (tid == 0 && blkc) sbase = atomicAdd(&acc->cursor[b*32], blkc);
  __syncthreads();
  // coalesced dense write (block order nondeterministic; selection is order-free)
  if (tid < blkc) dense[(size_t)b*AA + sbase + tid] = sv[tid];
}

// ---------- D5: per-image selection from DENSE survivors (16 x 1024) + final ----------
__global__ __launch_bounds__(1024) void ksel(const float* __restrict__ dense,
                                             const float* __restrict__ psum,
                                             Accum* acc, float* __restrict__ out) {
  __shared__ float ld[DCAP];
  __shared__ int h[2048];
  const int b = blockIdx.x;
  const int tid = threadIdx.x;
  const int npos = acc->npos[b];
  const int k = npos > 0 ? 100*npos : 100;
  const int B1 = acc->B1[b];
  const int cnt_above = acc->cnt_above[b];
  const float pos_sum = acc->pos_sum[b];

  const float pv = (tid < NSEG) ? psum[b*NSEG + tid] : 0.0f;
  const float sum_above = redF1024(pv);

  if (B1 < 1024) {   // k-th value negative: only nonneg values counted
    if (tid == 0) acc->per_img[b] = (pos_sum + sum_above) / fmaxf((float)npos, 1.0f);
  } else {
    const int S = acc->cursor[b*32];
    const float* db = dense + (size_t)b*AA;
    const bool fits = (S <= DCAP);
    if (fits) {
      for (int i = tid; i < S; i += 1024) ld[i] = db[i];   // coalesced, few lines
    }
    h[tid] = 0; h[tid + 1024] = 0;
    __syncthreads();
    const int kt2 = k - cnt_above;   // >= 1
    __shared__ int sB2, sC2, sB3, sC3;

    // pass 1: level-2 hist (key bits 20..10), wave-aggregated (skewed bins)
    for (int i0 = 0; i0 < S; i0 += 1024) {
      const int i = i0 + tid;
      const float v = (i < S) ? (fits ? ld[i] : db[i]) : 0.0f;
      agg_lds_add(h, (i < S) ? (int)((fkey(v) >> 10) & 0x7FF) : -1);
    }
    __syncthreads();
    suffix_find_1024(h, 2048, kt2, &sB2, &sC2);
    const int B2 = sB2;
    const int kt3 = kt2 - sC2;       // >= 1
    h[tid] = 0;
    __syncthreads();

    // pass 2: msum/mcnt for sub > B2; level-3 hist (aggregated) for sub == B2
    float msum = 0.0f; int mcnt = 0;
    for (int i0 = 0; i0 < S; i0 += 1024) {
      const int i = i0 + tid;
      int bin3 = -1;
      if (i < S) {
        const float v = fits ? ld[i] : db[i];
        const unsigned key = fkey(v);
        const int sub = (int)((key >> 10) & 0x7FF);
        if (sub > B2) { msum += v; mcnt++; }
        else if (sub == B2) bin3 = (int)(key & 0x3FF);
      }
      agg_lds_add(h, bin3);
    }
    __syncthreads();
    suffix_find_1024(h, 1024, kt3, &sB3, &sC3);
    const int B3 = sB3;
    const unsigned Kstar = ((unsigned)B1 << 21) | ((unsigned)B2 << 10) | (unsigned)B3;
    const float vK = fkey_inv(Kstar);  // >= 0 since B1 >= 1024

    // pass 3: count/sum of sub == B2 with low bits > B3
    for (int i0 = 0; i0 < S; i0 += 1024) {
      const int i = i0 + tid;
      if (i < S) {
        const float x = fits ? ld[i] : db[i];
        const unsigned key = fkey(x);
        if ((int)((key >> 10) & 0x7FF) == B2 && (int)(key & 0x3FF) > B3) { msum += x; mcnt++; }
      }
    }
    const int cg = redI1024(mcnt);
    const float sg = redF1024(msum);
    if (tid == 0) {
      const int total_gt = cnt_above + cg;
      const float ns = sum_above + sg + (float)(k - total_gt) * vK;
      acc->per_img[b] = (pos_sum + ns) / fmaxf((float)npos, 1.0f);
    }
  }

  // fused final: last of the 16 blocks writes out[0..3] (fences in 16 blocks only)
  __threadfence();
  __shared__ int lastAll;
  if (tid == 0) lastAll = (atomicAdd(&acc->done, 1) == BB - 1) ? 1 : 0;
  __syncthreads();
  if (!lastAll) return;
  __threadfence();
  if (tid == 0) {
    float s = 0.0f; int tot = 0;
    for (int b2 = 0; b2 < BB; ++b2) { s += acc->per_img[b2]; tot += acc->npos[b2]; }
    out[0] = s / (float)BB;
    const float denom = fmaxf((float)tot, 1.0f);
    out[1] = acc->shape_sum / (denom * 3.0f);
    out[2] = acc->off_sum / (denom * 3.0f);
    out[3] = 1.0f - acc->iou_sum / denom;
  }
}

extern "C" void kernel_launch(void* const* d_in, const int* in_sizes, int n_in,
                              void* d_out, int out_size, void* d_ws, size_t ws_size,
                              hipStream_t stream) {
  const float* cls_out    = (const float*)d_in[0];
  const float* shape_out  = (const float*)d_in[1];
  const float* offset_out = (const float*)d_in[2];
  const float* ann        = (const float*)d_in[3];
  float* out = (float*)d_out;

  char* ws = (char*)d_ws;
  Accum* acc    = (Accum*)ws;                               // ~2.6 KB
  int* plist    = (int*)(ws + 8192);                        // 128*7   = 3.6 KB
  int* ilist    = plist + (size_t)BB*NN*TOPKc;              // 128*182 = 93 KB
  int* ghist    = ilist + (size_t)BB*NN*NIGN;               // 32768   = 128 KB
  float* neg    = (float*)(ghist + (size_t)BB*NB1);         // 3.54 MB
  float* dense  = neg + (size_t)BB*AA;                      // 3.54 MB
  float* psum   = dense + (size_t)BB*AA;                    // 13.8 KB

  hipLaunchKernelGGL(k2_topk, dim3(BB*NN), dim3(256), 0, stream,
                     ann, plist, ilist, ghist, acc);
  hipLaunchKernelGGL(k3_loss, dim3(NBLK), dim3(256), 0, stream,
                     cls_out, shape_out, offset_out, ann, plist, ilist, neg, ghist, acc);
  hipLaunchKernelGGL(ks1, dim3(BB), dim3(256), 0, stream, ghist, acc);
  hipLaunchKernelGGL(kgather, dim3(NBLK), dim3(256), 0, stream,
                     neg, dense, psum, acc);
  hipLaunchKernelGGL(ksel, dim3(BB), dim3(1024), 0, stream,
                     dense, psum, acc, out);
}